// Round 1
// baseline (835.855 us; speedup 1.0000x reference)
//
#include <hip/hip_runtime.h>
#include <math.h>

#define NP 20000
#define NG 5000
#define NTOT 25000
#define DF 512
#define NCLS 1000
#define DH 128
#define EPP 240000
#define EPG 100000
#define EGP 100000
#define ETOT 440000

// ---------------- histogram of degrees + homogeneous dst counts ----------------
__global__ void hist_kernel(const int* __restrict__ src_pp, const int* __restrict__ dst_pp,
                            const int* __restrict__ src_pg, const int* __restrict__ dst_pg,
                            const int* __restrict__ src_gp, const int* __restrict__ dst_gp,
                            int* outdeg_pp, int* outdeg_pg, int* outdeg_gp,
                            int* indeg_pp, int* indeg_gp, int* indeg_pg,
                            int* cnt)
{
    int e = blockIdx.x * blockDim.x + threadIdx.x;
    if (e < EPP) {
        int s = src_pp[e], d = dst_pp[e];
        atomicAdd(&outdeg_pp[s], 1); atomicAdd(&indeg_pp[d], 1); atomicAdd(&cnt[d], 1);
    } else if (e < EPP + EPG) {
        int i = e - EPP; int s = src_pg[i], d = dst_pg[i];
        atomicAdd(&outdeg_pg[s], 1); atomicAdd(&indeg_pg[d], 1); atomicAdd(&cnt[NP + d], 1);
    } else if (e < ETOT) {
        int i = e - EPP - EPG; int s = src_gp[i], d = dst_gp[i];
        atomicAdd(&outdeg_gp[s], 1); atomicAdd(&indeg_gp[d], 1); atomicAdd(&cnt[d], 1);
    }
}

// ---------------- exclusive scan of cnt[NTOT] -> row_ptr[NTOT+1] ----------------
__global__ __launch_bounds__(1024) void scan_kernel(const int* __restrict__ cnt, int* __restrict__ row_ptr)
{
    __shared__ int part[1024];
    int t = threadIdx.x;
    const int CH = (NTOT + 1023) / 1024;  // 25
    int base = t * CH;
    int s = 0;
    for (int i = 0; i < CH; i++) { int idx = base + i; if (idx < NTOT) s += cnt[idx]; }
    part[t] = s;
    __syncthreads();
    for (int off = 1; off < 1024; off <<= 1) {
        int v = (t >= off) ? part[t - off] : 0;
        __syncthreads();
        part[t] += v;
        __syncthreads();
    }
    int run = (t == 0) ? 0 : part[t - 1];
    for (int i = 0; i < CH; i++) {
        int idx = base + i;
        if (idx < NTOT) { row_ptr[idx] = run; run += cnt[idx]; }
    }
    if (t == 1023) row_ptr[NTOT] = part[1023];
}

// ---------------- scatter edges into CSR (payload = src | etype<<16, + src GCN scale) ----------------
__global__ void scatter_kernel(const int* __restrict__ src_pp, const int* __restrict__ dst_pp,
                               const int* __restrict__ src_pg, const int* __restrict__ dst_pg,
                               const int* __restrict__ src_gp, const int* __restrict__ dst_gp,
                               const int* __restrict__ outdeg_pp, const int* __restrict__ outdeg_pg,
                               const int* __restrict__ outdeg_gp,
                               const int* __restrict__ row_ptr, int* fill,
                               int* __restrict__ payload, float* __restrict__ escale)
{
    int e = blockIdx.x * blockDim.x + threadIdx.x;
    int s, d, t; float sc;
    if (e < EPP) {
        s = src_pp[e]; d = dst_pp[e]; t = 0;
        sc = rsqrtf((float)max(outdeg_pp[s], 1));
    } else if (e < EPP + EPG) {
        int i = e - EPP; s = src_pg[i]; d = NP + dst_pg[i]; t = 1;
        sc = rsqrtf((float)max(outdeg_pg[s], 1));
    } else if (e < ETOT) {
        int i = e - EPP - EPG; int sl = src_gp[i]; s = NP + sl; d = dst_gp[i]; t = 2;
        sc = rsqrtf((float)max(outdeg_gp[sl], 1));
    } else return;
    int pos = row_ptr[d] + atomicAdd(&fill[d], 1);
    payload[pos] = s | (t << 16);
    escale[pos] = sc;
}

// ---------------- GEMM [M,K]@[K,128] + bias, then row l2-norm ----------------
__global__ __launch_bounds__(128) void gemm_ln_kernel(const float* __restrict__ A, int K,
                                                      const float* __restrict__ W, const float* __restrict__ b,
                                                      float* __restrict__ out, int M)
{
    const int j = threadIdx.x;
    const int row0 = blockIdx.x * 16;
    __shared__ float a_l[16][256];
    float acc[16];
#pragma unroll
    for (int r = 0; r < 16; r++) acc[r] = 0.f;
    for (int kc = 0; kc < K; kc += 256) {
        int kmax = min(256, K - kc);
        for (int l = j; l < 16 * 256; l += 128) {
            int r = l >> 8, k = l & 255;
            int row = row0 + r;
            float v = 0.f;
            if (k < kmax && row < M) v = A[(size_t)row * K + kc + k];
            a_l[r][k] = v;
        }
        __syncthreads();
        for (int k = 0; k < kmax; k++) {
            float w = W[(size_t)(kc + k) * DH + j];
#pragma unroll
            for (int r = 0; r < 16; r++) acc[r] += w * a_l[r][k];
        }
        __syncthreads();
    }
    float bj = b[j];
#pragma unroll
    for (int r = 0; r < 16; r++) acc[r] += bj;

    __shared__ float rsum[2][16];
    int wid = j >> 6, lane = j & 63;
#pragma unroll
    for (int r = 0; r < 16; r++) {
        float v = acc[r] * acc[r];
        for (int off = 32; off > 0; off >>= 1) v += __shfl_xor(v, off);
        if (lane == 0) rsum[wid][r] = v;
    }
    __syncthreads();
#pragma unroll
    for (int r = 0; r < 16; r++) {
        int row = row0 + r;
        if (row < M) {
            float ss = rsum[0][r] + rsum[1][r];
            float scale = 1.f / fmaxf(sqrtf(ss), 1e-12f);
            out[(size_t)row * DH + j] = acc[r] * scale;
        }
    }
}

// ---------------- GCN aggregation onto protein dst nodes (rst_pp, rst_gp) ----------------
__global__ __launch_bounds__(128) void rst_agg_kernel(const float* __restrict__ x,
                                                      const int* __restrict__ row_ptr,
                                                      const int* __restrict__ payload,
                                                      const float* __restrict__ escale,
                                                      const int* __restrict__ indeg_pp,
                                                      const int* __restrict__ indeg_gp,
                                                      float* __restrict__ rpp, float* __restrict__ rgp)
{
    int d = blockIdx.x;  // < NP
    int c = threadIdx.x;
    int beg = row_ptr[d], end = row_ptr[d + 1];
    float spp = 0.f, sgp = 0.f;
    __shared__ int pl[128];
    __shared__ float sc[128];
    for (int base = beg; base < end; base += 128) {
        int n = min(128, end - base);
        __syncthreads();
        if (c < n) { pl[c] = payload[base + c]; sc[c] = escale[base + c]; }
        __syncthreads();
        for (int i = 0; i < n; i++) {
            int p = pl[i]; int s = p & 0xFFFF; int t = p >> 16;
            float v = x[(size_t)s * DH + c] * sc[i];
            if (t == 0) spp += v; else sgp += v;  // t==2 (gp); t==1 never targets proteins
        }
    }
    float ipp = rsqrtf((float)max(indeg_pp[d], 1));
    float igp = rsqrtf((float)max(indeg_gp[d], 1));
    rpp[(size_t)d * DH + c] = spp * ipp;
    rgp[(size_t)d * DH + c] = sgp * igp;
}

// ---------------- ea = elu(Hd@Wl + bl + R@Wr + br), in-place over R ----------------
__global__ __launch_bounds__(128) void ea_gemm_kernel(const float* __restrict__ Hd, const float* __restrict__ R,
                                                      const float* __restrict__ Wl, const float* __restrict__ bl,
                                                      const float* __restrict__ Wr, const float* __restrict__ br,
                                                      float* __restrict__ out, int M)
{
    int j = threadIdx.x;
    int row0 = blockIdx.x * 16;
    __shared__ float hd_l[16][DH];
    __shared__ float r_l[16][DH];
    for (int l = j; l < 16 * DH; l += 128) {
        int r = l >> 7, k = l & 127; int row = row0 + r;
        hd_l[r][k] = (row < M) ? Hd[(size_t)row * DH + k] : 0.f;
        r_l[r][k]  = (row < M) ? R[(size_t)row * DH + k] : 0.f;
    }
    __syncthreads();
    float acc[16];
    float bj = bl[j] + br[j];
#pragma unroll
    for (int r = 0; r < 16; r++) acc[r] = bj;
    for (int k = 0; k < DH; k++) {
        float wl = Wl[(size_t)k * DH + j];
        float wr = Wr[(size_t)k * DH + j];
#pragma unroll
        for (int r = 0; r < 16; r++) acc[r] += wl * hd_l[r][k] + wr * r_l[r][k];
    }
    for (int r = 0; r < 16; r++) {
        int row = row0 + r;
        if (row < M) {
            float v = acc[r];
            out[(size_t)row * DH + j] = v > 0.f ? v : (expf(v) - 1.f);
        }
    }
}

// ---------------- per-(protein,channel) type-level alpha weights, in-place over ea ----------------
__global__ void wa_kernel(const int* __restrict__ indeg_pp, const int* __restrict__ indeg_gp,
                          float* __restrict__ eapp, float* __restrict__ eagp)
{
    int idx = blockIdx.x * blockDim.x + threadIdx.x;
    if (idx >= NP * DH) return;
    int d = idx >> 7;
    int npp = indeg_pp[d], ngp = indeg_gp[d];
    float app = eapp[idx], agp = eagp[idx];
    float wpp = 0.f, wgp = 0.f;
    if (npp > 0 && ngp > 0) {
        float mx = fmaxf(app, agp);
        float epp = expf(app - mx), egp = expf(agp - mx);
        float den = (float)npp * epp + (float)ngp * egp;
        wpp = epp / den; wgp = egp / den;
    } else if (npp > 0) wpp = 1.f / (float)npp;
    else if (ngp > 0) wgp = 1.f / (float)ngp;
    eapp[idx] = wpp;
    eagp[idx] = wgp;
}

// ---------------- hl = x@Wnl+bnl, hr = x@Wnr+bnr ----------------
__global__ __launch_bounds__(128) void hlr_gemm_kernel(const float* __restrict__ x,
                                                       const float* __restrict__ Wnl, const float* __restrict__ bnl,
                                                       const float* __restrict__ Wnr, const float* __restrict__ bnr,
                                                       float* __restrict__ hl, float* __restrict__ hr, int M)
{
    int j = threadIdx.x;
    int row0 = blockIdx.x * 16;
    __shared__ float x_l[16][DH];
    for (int l = j; l < 16 * DH; l += 128) {
        int r = l >> 7, k = l & 127; int row = row0 + r;
        x_l[r][k] = (row < M) ? x[(size_t)row * DH + k] : 0.f;
    }
    __syncthreads();
    float accl[16], accr[16];
    float bjl = bnl[j], bjr = bnr[j];
#pragma unroll
    for (int r = 0; r < 16; r++) { accl[r] = bjl; accr[r] = bjr; }
    for (int k = 0; k < DH; k++) {
        float wl = Wnl[(size_t)k * DH + j];
        float wr = Wnr[(size_t)k * DH + j];
#pragma unroll
        for (int r = 0; r < 16; r++) {
            float xv = x_l[r][k];
            accl[r] += wl * xv;
            accr[r] += wr * xv;
        }
    }
    for (int r = 0; r < 16; r++) {
        int row = row0 + r;
        if (row < M) {
            hl[(size_t)row * DH + j] = accl[r];
            hr[(size_t)row * DH + j] = accr[r];
        }
    }
}

// ---------------- node attention: online softmax over incoming edges + aggregation ----------------
__global__ __launch_bounds__(128) void node_attn_kernel(const float* __restrict__ x,
                                                        const float* __restrict__ hl, const float* __restrict__ hr,
                                                        const float* __restrict__ wpp_arr, const float* __restrict__ wgp_arr,
                                                        const int* __restrict__ indeg_pg,
                                                        const int* __restrict__ row_ptr, const int* __restrict__ payload,
                                                        float* __restrict__ h)
{
    int d = blockIdx.x, c = threadIdx.x;
    int beg = row_ptr[d], end = row_ptr[d + 1];
    float hrd = hr[(size_t)d * DH + c];
    float wpp = 0.f, wgp = 0.f, wpg = 0.f;
    if (d < NP) {
        wpp = wpp_arr[(size_t)d * DH + c];
        wgp = wgp_arr[(size_t)d * DH + c];
    } else {
        wpg = 1.f / (float)max(indeg_pg[d - NP], 1);
    }
    float m = -INFINITY, ssum = 0.f, acc = 0.f;
    __shared__ int pl[128];
    for (int base = beg; base < end; base += 128) {
        int n = min(128, end - base);
        __syncthreads();
        if (c < n) pl[c] = payload[base + c];
        __syncthreads();
        for (int i = 0; i < n; i++) {
            int p = pl[i]; int s = p & 0xFFFF; int t = p >> 16;
            float al = (d < NP) ? (t == 0 ? wpp : wgp) : wpg;
            float e = (hl[(size_t)s * DH + c] + hrd) * al;
            e = e > 0.f ? e : -0.2f * e;   // LeakyReLU, slope = -0.2
            float xv = x[(size_t)s * DH + c];
            if (e > m) {
                float r0 = expf(m - e);
                ssum = ssum * r0 + 1.f;
                acc = acc * r0 + xv;
                m = e;
            } else {
                float p2 = expf(e - m);
                ssum += p2;
                acc += p2 * xv;
            }
        }
    }
    h[(size_t)d * DH + c] = (end > beg) ? acc / ssum : 0.f;
}

// ---------------- out = h@Wfc + bfc ----------------
__global__ __launch_bounds__(256) void out_gemm_kernel(const float* __restrict__ h,
                                                       const float* __restrict__ Wfc, const float* __restrict__ bfc,
                                                       float* __restrict__ out)
{
    int row0 = blockIdx.x * 16;
    int c = blockIdx.y * 256 + threadIdx.x;
    __shared__ float h_l[16][DH];
    for (int l = threadIdx.x; l < 16 * DH; l += 256) {
        int r = l >> 7, k = l & 127; int row = row0 + r;
        h_l[r][k] = (row < NTOT) ? h[(size_t)row * DH + k] : 0.f;
    }
    __syncthreads();
    if (c >= NCLS) return;
    float acc[16];
    float bc = bfc[c];
#pragma unroll
    for (int r = 0; r < 16; r++) acc[r] = bc;
    for (int k = 0; k < DH; k++) {
        float w = Wfc[(size_t)k * NCLS + c];
#pragma unroll
        for (int r = 0; r < 16; r++) acc[r] += w * h_l[r][k];
    }
    for (int r = 0; r < 16; r++) {
        int row = row0 + r;
        if (row < NTOT) out[(size_t)row * NCLS + c] = acc[r];
    }
}

extern "C" void kernel_launch(void* const* d_in, const int* in_sizes, int n_in,
                              void* d_out, int out_size, void* d_ws, size_t ws_size,
                              hipStream_t stream)
{
    const float* x_protein = (const float*)d_in[0];
    const float* x_go      = (const float*)d_in[1];
    const int* src_pp = (const int*)d_in[2];
    const int* dst_pp = (const int*)d_in[3];
    const int* src_pg = (const int*)d_in[4];
    const int* dst_pg = (const int*)d_in[5];
    const int* src_gp = (const int*)d_in[6];
    const int* dst_gp = (const int*)d_in[7];
    const float* W1p = (const float*)d_in[8];
    const float* b1p = (const float*)d_in[9];
    const float* W1g = (const float*)d_in[10];
    const float* b1g = (const float*)d_in[11];
    const float* Wl_p = (const float*)d_in[12];
    const float* bl_p = (const float*)d_in[13];
    // Wl_g (14), bl_g (15) are dead: go-dst alpha is uniform 1/n
    const float* Wr_p = (const float*)d_in[16];
    const float* br_p = (const float*)d_in[17];
    const float* Wr_g = (const float*)d_in[18];
    const float* br_g = (const float*)d_in[19];
    const float* Wnl = (const float*)d_in[20];
    const float* bnl = (const float*)d_in[21];
    const float* Wnr = (const float*)d_in[22];
    const float* bnr = (const float*)d_in[23];
    const float* Wfc = (const float*)d_in[24];
    const float* bfc = (const float*)d_in[25];
    float* out = (float*)d_out;

    // ---- workspace layout ----
    float* x    = (float*)d_ws;            // NTOT*DH
    float* hl   = x + (size_t)NTOT * DH;   // NTOT*DH
    float* hr   = hl + (size_t)NTOT * DH;  // NTOT*DH
    float* rpp  = hr + (size_t)NTOT * DH;  // NP*DH  (rst_pp -> ea_pp -> wa_pp)
    float* rgp  = rpp + (size_t)NP * DH;   // NP*DH  (rst_gp -> ea_gp -> wa_gp)
    float* hagg = rgp + (size_t)NP * DH;   // NTOT*DH
    int* ibase = (int*)(hagg + (size_t)NTOT * DH);
    int* outdeg_pp = ibase;                 // NP
    int* outdeg_pg = outdeg_pp + NP;        // NP
    int* outdeg_gp = outdeg_pg + NP;        // NG
    int* indeg_pp  = outdeg_gp + NG;        // NP
    int* indeg_gp  = indeg_pp + NP;         // NP
    int* indeg_pg  = indeg_gp + NP;         // NG
    int* cnt       = indeg_pg + NG;         // NTOT
    int* fill      = cnt + NTOT;            // NTOT
    int* row_ptr   = fill + NTOT;           // NTOT+1
    int* payload   = row_ptr + NTOT + 1;    // ETOT
    float* escale  = (float*)(payload + ETOT);  // ETOT

    // zero the counters (outdeg..fill contiguous = 4*NP + 2*NG + 2*NTOT = 140000 ints)
    hipMemsetAsync(ibase, 0, (size_t)140000 * sizeof(int), stream);

    const int EB = (ETOT + 255) / 256;
    hist_kernel<<<EB, 256, 0, stream>>>(src_pp, dst_pp, src_pg, dst_pg, src_gp, dst_gp,
                                        outdeg_pp, outdeg_pg, outdeg_gp,
                                        indeg_pp, indeg_gp, indeg_pg, cnt);
    scan_kernel<<<1, 1024, 0, stream>>>(cnt, row_ptr);
    scatter_kernel<<<EB, 256, 0, stream>>>(src_pp, dst_pp, src_pg, dst_pg, src_gp, dst_gp,
                                           outdeg_pp, outdeg_pg, outdeg_gp,
                                           row_ptr, fill, payload, escale);

    // input projections + l2norm
    gemm_ln_kernel<<<NP / 16, 128, 0, stream>>>(x_protein, DF, W1p, b1p, x, NP);
    gemm_ln_kernel<<<(NG + 15) / 16, 128, 0, stream>>>(x_go, NCLS, W1g, b1g, x + (size_t)NP * DH, NG);

    // GCN aggregation for type attention (protein dst only; go-dst branch is dead)
    rst_agg_kernel<<<NP, 128, 0, stream>>>(x, row_ptr, payload, escale, indeg_pp, indeg_gp, rpp, rgp);

    // ea_pp, ea_gp (both use Hd = hp with Wl_p/bl_p)
    ea_gemm_kernel<<<NP / 16, 128, 0, stream>>>(x, rpp, Wl_p, bl_p, Wr_p, br_p, rpp, NP);
    ea_gemm_kernel<<<NP / 16, 128, 0, stream>>>(x, rgp, Wl_p, bl_p, Wr_g, br_g, rgp, NP);

    // type-level alpha weights
    wa_kernel<<<(NP * DH + 255) / 256, 256, 0, stream>>>(indeg_pp, indeg_gp, rpp, rgp);

    // node attention projections
    hlr_gemm_kernel<<<(NTOT + 15) / 16, 128, 0, stream>>>(x, Wnl, bnl, Wnr, bnr, hl, hr, NTOT);

    // node attention + aggregation
    node_attn_kernel<<<NTOT, 128, 0, stream>>>(x, hl, hr, rpp, rgp, indeg_pg, row_ptr, payload, hagg);

    // final classifier
    out_gemm_kernel<<<dim3((NTOT + 15) / 16, (NCLS + 255) / 256), 256, 0, stream>>>(hagg, Wfc, bfc, out);

    (void)in_sizes; (void)n_in; (void)out_size; (void)ws_size;
}

// Round 2
// 745.182 us; speedup vs baseline: 1.1217x; 1.1217x over previous
//
#include <hip/hip_runtime.h>
#include <math.h>

#define NP 20000
#define NG 5000
#define NTOT 25000
#define DF 512
#define NCLS 1000
#define DH 128
#define EPP 240000
#define EPG 100000
#define EGP 100000
#define ETOT 440000

typedef __attribute__((ext_vector_type(8))) __bf16 bf16x8;
typedef __attribute__((ext_vector_type(4))) float f32x4;

// ---------------- histogram of degrees + homogeneous dst counts ----------------
__global__ void hist_kernel(const int* __restrict__ src_pp, const int* __restrict__ dst_pp,
                            const int* __restrict__ src_pg, const int* __restrict__ dst_pg,
                            const int* __restrict__ src_gp, const int* __restrict__ dst_gp,
                            int* outdeg_pp, int* outdeg_pg, int* outdeg_gp,
                            int* indeg_pp, int* indeg_gp, int* indeg_pg,
                            int* cnt)
{
    int e = blockIdx.x * blockDim.x + threadIdx.x;
    if (e < EPP) {
        int s = src_pp[e], d = dst_pp[e];
        atomicAdd(&outdeg_pp[s], 1); atomicAdd(&indeg_pp[d], 1); atomicAdd(&cnt[d], 1);
    } else if (e < EPP + EPG) {
        int i = e - EPP; int s = src_pg[i], d = dst_pg[i];
        atomicAdd(&outdeg_pg[s], 1); atomicAdd(&indeg_pg[d], 1); atomicAdd(&cnt[NP + d], 1);
    } else if (e < ETOT) {
        int i = e - EPP - EPG; int s = src_gp[i], d = dst_gp[i];
        atomicAdd(&outdeg_gp[s], 1); atomicAdd(&indeg_gp[d], 1); atomicAdd(&cnt[d], 1);
    }
}

// ---------------- exclusive scan of cnt[NTOT] -> row_ptr[NTOT+1] ----------------
__global__ __launch_bounds__(1024) void scan_kernel(const int* __restrict__ cnt, int* __restrict__ row_ptr)
{
    __shared__ int part[1024];
    int t = threadIdx.x;
    const int CH = (NTOT + 1023) / 1024;  // 25
    int base = t * CH;
    int s = 0;
    for (int i = 0; i < CH; i++) { int idx = base + i; if (idx < NTOT) s += cnt[idx]; }
    part[t] = s;
    __syncthreads();
    for (int off = 1; off < 1024; off <<= 1) {
        int v = (t >= off) ? part[t - off] : 0;
        __syncthreads();
        part[t] += v;
        __syncthreads();
    }
    int run = (t == 0) ? 0 : part[t - 1];
    for (int i = 0; i < CH; i++) {
        int idx = base + i;
        if (idx < NTOT) { row_ptr[idx] = run; run += cnt[idx]; }
    }
    if (t == 1023) row_ptr[NTOT] = part[1023];
}

// ---------------- scatter edges into CSR (payload = src | etype<<16, + src GCN scale) ----------------
__global__ void scatter_kernel(const int* __restrict__ src_pp, const int* __restrict__ dst_pp,
                               const int* __restrict__ src_pg, const int* __restrict__ dst_pg,
                               const int* __restrict__ src_gp, const int* __restrict__ dst_gp,
                               const int* __restrict__ outdeg_pp, const int* __restrict__ outdeg_pg,
                               const int* __restrict__ outdeg_gp,
                               const int* __restrict__ row_ptr, int* fill,
                               int* __restrict__ payload, float* __restrict__ escale)
{
    int e = blockIdx.x * blockDim.x + threadIdx.x;
    int s, d, t; float sc;
    if (e < EPP) {
        s = src_pp[e]; d = dst_pp[e]; t = 0;
        sc = rsqrtf((float)max(outdeg_pp[s], 1));
    } else if (e < EPP + EPG) {
        int i = e - EPP; s = src_pg[i]; d = NP + dst_pg[i]; t = 1;
        sc = rsqrtf((float)max(outdeg_pg[s], 1));
    } else if (e < ETOT) {
        int i = e - EPP - EPG; int sl = src_gp[i]; s = NP + sl; d = dst_gp[i]; t = 2;
        sc = rsqrtf((float)max(outdeg_gp[sl], 1));
    } else return;
    int pos = row_ptr[d] + atomicAdd(&fill[d], 1);
    payload[pos] = s | (t << 16);
    escale[pos] = sc;
}

// =====================================================================
// Generic MFMA bf16 GEMM: O = act(A1@W1 [+ A2@W2] + bias)
//   ACT: 0 = none, 1 = ELU, 2 = row l2-norm (requires N==128, gridDim.y==1)
//   DUALA: acc += A2@W2 (bias = b1+b2)
//   DUALW: second output O2 = A1@W2 + b2
// Tile: 64 (M) x 128 (N), BK=32, 4 waves in 2x2 (wave -> 32x64 region,
// 2x4 frags of 16x16x32). A,W are fp32 in memory, converted to bf16 in LDS.
// =====================================================================
template<int ACT, int DUALA, int DUALW>
__global__ __launch_bounds__(256) void mfma_gemm_kernel(
    const float* __restrict__ A1, const float* __restrict__ A2,
    const float* __restrict__ W1, const float* __restrict__ W2,
    const float* __restrict__ b1, const float* __restrict__ b2,
    float* __restrict__ O1, float* __restrict__ O2,
    int M, int N, int K)
{
    __shared__ __align__(16) __bf16 A1s[64][40];
    __shared__ __align__(16) __bf16 A2s[DUALA ? 64 : 1][40];
    __shared__ __align__(16) __bf16 B1s[128][40];
    __shared__ __align__(16) __bf16 B2s[(DUALA || DUALW) ? 128 : 1][40];

    const int tid = threadIdx.x;
    const int wave = tid >> 6, lane = tid & 63;
    const int wr = wave >> 1, wc = wave & 1;
    const int l15 = lane & 15, lh = lane >> 4;
    const int row0 = blockIdx.x * 64;
    const int col0 = blockIdx.y * 128;

    f32x4 acc[2][4];
    f32x4 acc2[2][4];
#pragma unroll
    for (int fm = 0; fm < 2; fm++)
#pragma unroll
        for (int fn = 0; fn < 4; fn++) {
            acc[fm][fn] = (f32x4)0.f;
            if (DUALW) acc2[fm][fn] = (f32x4)0.f;
        }

    const int ar = tid >> 2, aq = tid & 3;       // A staging: row, k-octet
    const int bc = tid & 127, bh = tid >> 7;     // B staging: col, k-half

    for (int k0 = 0; k0 < K; k0 += 32) {
        __syncthreads();
        // ---- stage A1 (and A2): A[row0+ar][k0 + aq*8 .. +7] -> bf16 ----
        {
            int grow = row0 + ar;
            float f[8];
            const float* ap = A1 + (size_t)grow * K + k0 + aq * 8;
            if (grow < M && (k0 + aq * 8 + 8) <= K) {
                f32x4 v0 = *(const f32x4*)ap;
                f32x4 v1 = *(const f32x4*)(ap + 4);
#pragma unroll
                for (int i = 0; i < 4; i++) { f[i] = v0[i]; f[4 + i] = v1[i]; }
            } else {
#pragma unroll
                for (int i = 0; i < 8; i++) {
                    int k = k0 + aq * 8 + i;
                    f[i] = (grow < M && k < K) ? A1[(size_t)grow * K + k] : 0.f;
                }
            }
            __bf16 pk[8];
#pragma unroll
            for (int i = 0; i < 8; i++) pk[i] = (__bf16)f[i];
            *(bf16x8*)&A1s[ar][aq * 8] = *(bf16x8*)pk;

            if (DUALA) {
                const float* ap2 = A2 + (size_t)grow * K + k0 + aq * 8;
                if (grow < M && (k0 + aq * 8 + 8) <= K) {
                    f32x4 v0 = *(const f32x4*)ap2;
                    f32x4 v1 = *(const f32x4*)(ap2 + 4);
#pragma unroll
                    for (int i = 0; i < 4; i++) { f[i] = v0[i]; f[4 + i] = v1[i]; }
                } else {
#pragma unroll
                    for (int i = 0; i < 8; i++) {
                        int k = k0 + aq * 8 + i;
                        f[i] = (grow < M && k < K) ? A2[(size_t)grow * K + k] : 0.f;
                    }
                }
#pragma unroll
                for (int i = 0; i < 8; i++) pk[i] = (__bf16)f[i];
                *(bf16x8*)&A2s[ar][aq * 8] = *(bf16x8*)pk;
            }
        }
        // ---- stage B (k-major): B1s[c][k] = W1[k0+k][col0+c] ----
        {
            int col = col0 + bc;
            __bf16 pk[16];
#pragma unroll
            for (int kk = 0; kk < 16; kk++) {
                int k = k0 + bh * 16 + kk;
                float v = (col < N && k < K) ? W1[(size_t)k * N + col] : 0.f;
                pk[kk] = (__bf16)v;
            }
            *(bf16x8*)&B1s[bc][bh * 16] = *(bf16x8*)&pk[0];
            *(bf16x8*)&B1s[bc][bh * 16 + 8] = *(bf16x8*)&pk[8];
            if (DUALA || DUALW) {
#pragma unroll
                for (int kk = 0; kk < 16; kk++) {
                    int k = k0 + bh * 16 + kk;
                    float v = (col < N && k < K) ? W2[(size_t)k * N + col] : 0.f;
                    pk[kk] = (__bf16)v;
                }
                *(bf16x8*)&B2s[bc][bh * 16] = *(bf16x8*)&pk[0];
                *(bf16x8*)&B2s[bc][bh * 16 + 8] = *(bf16x8*)&pk[8];
            }
        }
        __syncthreads();
        // ---- compute ----
#pragma unroll
        for (int fm = 0; fm < 2; fm++) {
            bf16x8 a = *(const bf16x8*)&A1s[wr * 32 + fm * 16 + l15][lh * 8];
            bf16x8 a2;
            if (DUALA) a2 = *(const bf16x8*)&A2s[wr * 32 + fm * 16 + l15][lh * 8];
#pragma unroll
            for (int fn = 0; fn < 4; fn++) {
                bf16x8 b = *(const bf16x8*)&B1s[wc * 64 + fn * 16 + l15][lh * 8];
                acc[fm][fn] = __builtin_amdgcn_mfma_f32_16x16x32_bf16(a, b, acc[fm][fn], 0, 0, 0);
                if (DUALA) {
                    bf16x8 b2 = *(const bf16x8*)&B2s[wc * 64 + fn * 16 + l15][lh * 8];
                    acc[fm][fn] = __builtin_amdgcn_mfma_f32_16x16x32_bf16(a2, b2, acc[fm][fn], 0, 0, 0);
                }
                if (DUALW) {
                    bf16x8 b2 = *(const bf16x8*)&B2s[wc * 64 + fn * 16 + l15][lh * 8];
                    acc2[fm][fn] = __builtin_amdgcn_mfma_f32_16x16x32_bf16(a, b2, acc2[fm][fn], 0, 0, 0);
                }
            }
        }
    }

    // ---- epilogue ----
    float bias[4], bias2[4];
#pragma unroll
    for (int fn = 0; fn < 4; fn++) {
        int col = col0 + wc * 64 + fn * 16 + l15;
        bias[fn] = 0.f; bias2[fn] = 0.f;
        if (col < N) {
            bias[fn] = DUALA ? (b1[col] + b2[col]) : b1[col];
            if (DUALW) bias2[fn] = b2[col];
        }
    }

    float vv[2][4][4];
#pragma unroll
    for (int fm = 0; fm < 2; fm++)
#pragma unroll
        for (int fn = 0; fn < 4; fn++)
#pragma unroll
            for (int r = 0; r < 4; r++) {
                float v = acc[fm][fn][r] + bias[fn];
                if (ACT == 1) v = v > 0.f ? v : (expf(v) - 1.f);
                vv[fm][fn][r] = v;
            }

    float scale[2][4];
#pragma unroll
    for (int fm = 0; fm < 2; fm++)
#pragma unroll
        for (int r = 0; r < 4; r++) scale[fm][r] = 1.f;

    if (ACT == 2) {
        __shared__ float part[2][64];
        float s[2][4];
#pragma unroll
        for (int fm = 0; fm < 2; fm++)
#pragma unroll
            for (int r = 0; r < 4; r++) {
                float v = 0.f;
#pragma unroll
                for (int fn = 0; fn < 4; fn++) v += vv[fm][fn][r] * vv[fm][fn][r];
                v += __shfl_xor(v, 1);
                v += __shfl_xor(v, 2);
                v += __shfl_xor(v, 4);
                v += __shfl_xor(v, 8);
                s[fm][r] = v;
            }
        __syncthreads();
        if (l15 == 0) {
#pragma unroll
            for (int fm = 0; fm < 2; fm++)
#pragma unroll
                for (int r = 0; r < 4; r++)
                    part[wc][wr * 32 + fm * 16 + lh * 4 + r] = s[fm][r];
        }
        __syncthreads();
#pragma unroll
        for (int fm = 0; fm < 2; fm++)
#pragma unroll
            for (int r = 0; r < 4; r++) {
                int rl = wr * 32 + fm * 16 + lh * 4 + r;
                float ss = part[0][rl] + part[1][rl];
                scale[fm][r] = 1.f / fmaxf(sqrtf(ss), 1e-12f);
            }
    }

#pragma unroll
    for (int fm = 0; fm < 2; fm++)
#pragma unroll
        for (int fn = 0; fn < 4; fn++)
#pragma unroll
            for (int r = 0; r < 4; r++) {
                int row = row0 + wr * 32 + fm * 16 + lh * 4 + r;
                int col = col0 + wc * 64 + fn * 16 + l15;
                if (row < M && col < N) {
                    O1[(size_t)row * N + col] = vv[fm][fn][r] * scale[fm][r];
                    if (DUALW) O2[(size_t)row * N + col] = acc2[fm][fn][r] + bias2[fn];
                }
            }
}

// ---------------- GCN aggregation onto protein dst nodes (rst_pp, rst_gp) ----------------
__global__ __launch_bounds__(128) void rst_agg_kernel(const float* __restrict__ x,
                                                      const int* __restrict__ row_ptr,
                                                      const int* __restrict__ payload,
                                                      const float* __restrict__ escale,
                                                      const int* __restrict__ indeg_pp,
                                                      const int* __restrict__ indeg_gp,
                                                      float* __restrict__ rpp, float* __restrict__ rgp)
{
    int d = blockIdx.x;  // < NP
    int c = threadIdx.x;
    int beg = row_ptr[d], end = row_ptr[d + 1];
    float spp = 0.f, sgp = 0.f;
    __shared__ int pl[128];
    __shared__ float sc[128];
    for (int base = beg; base < end; base += 128) {
        int n = min(128, end - base);
        __syncthreads();
        if (c < n) { pl[c] = payload[base + c]; sc[c] = escale[base + c]; }
        __syncthreads();
        for (int i = 0; i < n; i++) {
            int p = pl[i]; int s = p & 0xFFFF; int t = p >> 16;
            float v = x[(size_t)s * DH + c] * sc[i];
            if (t == 0) spp += v; else sgp += v;  // t==2 (gp); t==1 never targets proteins
        }
    }
    float ipp = rsqrtf((float)max(indeg_pp[d], 1));
    float igp = rsqrtf((float)max(indeg_gp[d], 1));
    rpp[(size_t)d * DH + c] = spp * ipp;
    rgp[(size_t)d * DH + c] = sgp * igp;
}

// ---------------- per-(protein,channel) type-level alpha weights, in-place over ea ----------------
__global__ void wa_kernel(const int* __restrict__ indeg_pp, const int* __restrict__ indeg_gp,
                          float* __restrict__ eapp, float* __restrict__ eagp)
{
    int idx = blockIdx.x * blockDim.x + threadIdx.x;
    if (idx >= NP * DH) return;
    int d = idx >> 7;
    int npp = indeg_pp[d], ngp = indeg_gp[d];
    float app = eapp[idx], agp = eagp[idx];
    float wpp = 0.f, wgp = 0.f;
    if (npp > 0 && ngp > 0) {
        float mx = fmaxf(app, agp);
        float epp = expf(app - mx), egp = expf(agp - mx);
        float den = (float)npp * epp + (float)ngp * egp;
        wpp = epp / den; wgp = egp / den;
    } else if (npp > 0) wpp = 1.f / (float)npp;
    else if (ngp > 0) wgp = 1.f / (float)ngp;
    eapp[idx] = wpp;
    eagp[idx] = wgp;
}

// ---------------- node attention: online softmax over incoming edges + aggregation ----------------
__global__ __launch_bounds__(128) void node_attn_kernel(const float* __restrict__ x,
                                                        const float* __restrict__ hl, const float* __restrict__ hr,
                                                        const float* __restrict__ wpp_arr, const float* __restrict__ wgp_arr,
                                                        const int* __restrict__ indeg_pg,
                                                        const int* __restrict__ row_ptr, const int* __restrict__ payload,
                                                        float* __restrict__ h)
{
    int d = blockIdx.x, c = threadIdx.x;
    int beg = row_ptr[d], end = row_ptr[d + 1];
    float hrd = hr[(size_t)d * DH + c];
    float wpp = 0.f, wgp = 0.f, wpg = 0.f;
    if (d < NP) {
        wpp = wpp_arr[(size_t)d * DH + c];
        wgp = wgp_arr[(size_t)d * DH + c];
    } else {
        wpg = 1.f / (float)max(indeg_pg[d - NP], 1);
    }
    float m = -INFINITY, ssum = 0.f, acc = 0.f;
    __shared__ int pl[128];
    for (int base = beg; base < end; base += 128) {
        int n = min(128, end - base);
        __syncthreads();
        if (c < n) pl[c] = payload[base + c];
        __syncthreads();
        for (int i = 0; i < n; i++) {
            int p = pl[i]; int s = p & 0xFFFF; int t = p >> 16;
            float al = (d < NP) ? (t == 0 ? wpp : wgp) : wpg;
            float e = (hl[(size_t)s * DH + c] + hrd) * al;
            e = e > 0.f ? e : -0.2f * e;   // LeakyReLU, slope = -0.2
            float xv = x[(size_t)s * DH + c];
            if (e > m) {
                float r0 = expf(m - e);
                ssum = ssum * r0 + 1.f;
                acc = acc * r0 + xv;
                m = e;
            } else {
                float p2 = expf(e - m);
                ssum += p2;
                acc += p2 * xv;
            }
        }
    }
    h[(size_t)d * DH + c] = (end > beg) ? acc / ssum : 0.f;
}

extern "C" void kernel_launch(void* const* d_in, const int* in_sizes, int n_in,
                              void* d_out, int out_size, void* d_ws, size_t ws_size,
                              hipStream_t stream)
{
    const float* x_protein = (const float*)d_in[0];
    const float* x_go      = (const float*)d_in[1];
    const int* src_pp = (const int*)d_in[2];
    const int* dst_pp = (const int*)d_in[3];
    const int* src_pg = (const int*)d_in[4];
    const int* dst_pg = (const int*)d_in[5];
    const int* src_gp = (const int*)d_in[6];
    const int* dst_gp = (const int*)d_in[7];
    const float* W1p = (const float*)d_in[8];
    const float* b1p = (const float*)d_in[9];
    const float* W1g = (const float*)d_in[10];
    const float* b1g = (const float*)d_in[11];
    const float* Wl_p = (const float*)d_in[12];
    const float* bl_p = (const float*)d_in[13];
    // Wl_g (14), bl_g (15) are dead: go-dst alpha is uniform 1/n
    const float* Wr_p = (const float*)d_in[16];
    const float* br_p = (const float*)d_in[17];
    const float* Wr_g = (const float*)d_in[18];
    const float* br_g = (const float*)d_in[19];
    const float* Wnl = (const float*)d_in[20];
    const float* bnl = (const float*)d_in[21];
    const float* Wnr = (const float*)d_in[22];
    const float* bnr = (const float*)d_in[23];
    const float* Wfc = (const float*)d_in[24];
    const float* bfc = (const float*)d_in[25];
    float* out = (float*)d_out;

    // ---- workspace layout ----
    float* x    = (float*)d_ws;            // NTOT*DH
    float* hl   = x + (size_t)NTOT * DH;   // NTOT*DH
    float* hr   = hl + (size_t)NTOT * DH;  // NTOT*DH
    float* rpp  = hr + (size_t)NTOT * DH;  // NP*DH  (rst_pp -> ea_pp -> wa_pp)
    float* rgp  = rpp + (size_t)NP * DH;   // NP*DH  (rst_gp -> ea_gp -> wa_gp)
    float* hagg = rgp + (size_t)NP * DH;   // NTOT*DH
    int* ibase = (int*)(hagg + (size_t)NTOT * DH);
    int* outdeg_pp = ibase;                 // NP
    int* outdeg_pg = outdeg_pp + NP;        // NP
    int* outdeg_gp = outdeg_pg + NP;        // NG
    int* indeg_pp  = outdeg_gp + NG;        // NP
    int* indeg_gp  = indeg_pp + NP;         // NP
    int* indeg_pg  = indeg_gp + NP;         // NG
    int* cnt       = indeg_pg + NG;         // NTOT
    int* fill      = cnt + NTOT;            // NTOT
    int* row_ptr   = fill + NTOT;           // NTOT+1
    int* payload   = row_ptr + NTOT + 1;    // ETOT
    float* escale  = (float*)(payload + ETOT);  // ETOT

    // zero the counters (outdeg..fill contiguous = 4*NP + 2*NG + 2*NTOT = 140000 ints)
    hipMemsetAsync(ibase, 0, (size_t)140000 * sizeof(int), stream);

    const int EB = (ETOT + 255) / 256;
    hist_kernel<<<EB, 256, 0, stream>>>(src_pp, dst_pp, src_pg, dst_pg, src_gp, dst_gp,
                                        outdeg_pp, outdeg_pg, outdeg_gp,
                                        indeg_pp, indeg_gp, indeg_pg, cnt);
    scan_kernel<<<1, 1024, 0, stream>>>(cnt, row_ptr);
    scatter_kernel<<<EB, 256, 0, stream>>>(src_pp, dst_pp, src_pg, dst_pg, src_gp, dst_gp,
                                           outdeg_pp, outdeg_pg, outdeg_gp,
                                           row_ptr, fill, payload, escale);

    // input projections + l2norm (MFMA bf16)
    mfma_gemm_kernel<2, 0, 0><<<dim3((NP + 63) / 64, 1), 256, 0, stream>>>(
        x_protein, nullptr, W1p, nullptr, b1p, nullptr, x, nullptr, NP, DH, DF);
    mfma_gemm_kernel<2, 0, 0><<<dim3((NG + 63) / 64, 1), 256, 0, stream>>>(
        x_go, nullptr, W1g, nullptr, b1g, nullptr, x + (size_t)NP * DH, nullptr, NG, DH, NCLS);

    // GCN aggregation for type attention (protein dst only; go-dst branch is dead)
    rst_agg_kernel<<<NP, 128, 0, stream>>>(x, row_ptr, payload, escale, indeg_pp, indeg_gp, rpp, rgp);

    // ea = elu(x@Wl_p + R@Wr_* + bl_p + br_*), in-place over R  (MFMA, dual-A)
    mfma_gemm_kernel<1, 1, 0><<<dim3((NP + 63) / 64, 1), 256, 0, stream>>>(
        x, rpp, Wl_p, Wr_p, bl_p, br_p, rpp, nullptr, NP, DH, DH);
    mfma_gemm_kernel<1, 1, 0><<<dim3((NP + 63) / 64, 1), 256, 0, stream>>>(
        x, rgp, Wl_p, Wr_g, bl_p, br_g, rgp, nullptr, NP, DH, DH);

    // type-level alpha weights
    wa_kernel<<<(NP * DH + 255) / 256, 256, 0, stream>>>(indeg_pp, indeg_gp, rpp, rgp);

    // node attention projections: hl = x@Wnl+bnl, hr = x@Wnr+bnr  (MFMA, dual-W)
    mfma_gemm_kernel<0, 0, 1><<<dim3((NTOT + 63) / 64, 1), 256, 0, stream>>>(
        x, nullptr, Wnl, Wnr, bnl, bnr, hl, hr, NTOT, DH, DH);

    // node attention + aggregation
    node_attn_kernel<<<NTOT, 128, 0, stream>>>(x, hl, hr, rpp, rgp, indeg_pg, row_ptr, payload, hagg);

    // final classifier: out = hagg@Wfc + bfc  (MFMA)
    mfma_gemm_kernel<0, 0, 0><<<dim3((NTOT + 63) / 64, (NCLS + 127) / 128), 256, 0, stream>>>(
        hagg, nullptr, Wfc, nullptr, bfc, nullptr, out, nullptr, NTOT, NCLS, DH);

    (void)in_sizes; (void)n_in; (void)out_size; (void)ws_size;
}

// Round 3
// 345.299 us; speedup vs baseline: 2.4207x; 2.1581x over previous
//
#include <hip/hip_runtime.h>
#include <math.h>

#define NP 20000
#define NG 5000
#define NTOT 25000
#define DF 512
#define NCLS 1000
#define DH 128
#define EPP 240000
#define EPG 100000
#define EGP 100000
#define ETOT 440000

typedef __attribute__((ext_vector_type(8))) __bf16 bf16x8;
typedef __attribute__((ext_vector_type(4))) float f32x4;

// async global->LDS, 16B per lane; LDS dest = wave-uniform base + lane*16
__device__ __forceinline__ void gl2lds16(const void* g, void* l) {
    __builtin_amdgcn_global_load_lds(
        (const __attribute__((address_space(1))) unsigned int*)g,
        (__attribute__((address_space(3))) unsigned int*)l, 16, 0, 0);
}

// ---------------- histogram of degrees + homogeneous dst counts ----------------
__global__ void hist_kernel(const int* __restrict__ src_pp, const int* __restrict__ dst_pp,
                            const int* __restrict__ src_pg, const int* __restrict__ dst_pg,
                            const int* __restrict__ src_gp, const int* __restrict__ dst_gp,
                            int* outdeg_pp, int* outdeg_pg, int* outdeg_gp,
                            int* indeg_pp, int* indeg_gp, int* indeg_pg,
                            int* cnt)
{
    int e = blockIdx.x * blockDim.x + threadIdx.x;
    if (e < EPP) {
        int s = src_pp[e], d = dst_pp[e];
        atomicAdd(&outdeg_pp[s], 1); atomicAdd(&indeg_pp[d], 1); atomicAdd(&cnt[d], 1);
    } else if (e < EPP + EPG) {
        int i = e - EPP; int s = src_pg[i], d = dst_pg[i];
        atomicAdd(&outdeg_pg[s], 1); atomicAdd(&indeg_pg[d], 1); atomicAdd(&cnt[NP + d], 1);
    } else if (e < ETOT) {
        int i = e - EPP - EPG; int s = src_gp[i], d = dst_gp[i];
        atomicAdd(&outdeg_gp[s], 1); atomicAdd(&indeg_gp[d], 1); atomicAdd(&cnt[d], 1);
    }
}

// ---------------- exclusive scan of cnt[NTOT] -> row_ptr[NTOT+1] ----------------
__global__ __launch_bounds__(1024) void scan_kernel(const int* __restrict__ cnt, int* __restrict__ row_ptr)
{
    __shared__ int part[1024];
    int t = threadIdx.x;
    const int CH = (NTOT + 1023) / 1024;  // 25
    int base = t * CH;
    int s = 0;
    for (int i = 0; i < CH; i++) { int idx = base + i; if (idx < NTOT) s += cnt[idx]; }
    part[t] = s;
    __syncthreads();
    for (int off = 1; off < 1024; off <<= 1) {
        int v = (t >= off) ? part[t - off] : 0;
        __syncthreads();
        part[t] += v;
        __syncthreads();
    }
    int run = (t == 0) ? 0 : part[t - 1];
    for (int i = 0; i < CH; i++) {
        int idx = base + i;
        if (idx < NTOT) { row_ptr[idx] = run; run += cnt[idx]; }
    }
    if (t == 1023) row_ptr[NTOT] = part[1023];
}

// ---------------- scatter edges into CSR ----------------
__global__ void scatter_kernel(const int* __restrict__ src_pp, const int* __restrict__ dst_pp,
                               const int* __restrict__ src_pg, const int* __restrict__ dst_pg,
                               const int* __restrict__ src_gp, const int* __restrict__ dst_gp,
                               const int* __restrict__ outdeg_pp, const int* __restrict__ outdeg_pg,
                               const int* __restrict__ outdeg_gp,
                               const int* __restrict__ row_ptr, int* fill,
                               int* __restrict__ payload, float* __restrict__ escale)
{
    int e = blockIdx.x * blockDim.x + threadIdx.x;
    int s, d, t; float sc;
    if (e < EPP) {
        s = src_pp[e]; d = dst_pp[e]; t = 0;
        sc = rsqrtf((float)max(outdeg_pp[s], 1));
    } else if (e < EPP + EPG) {
        int i = e - EPP; s = src_pg[i]; d = NP + dst_pg[i]; t = 1;
        sc = rsqrtf((float)max(outdeg_pg[s], 1));
    } else if (e < ETOT) {
        int i = e - EPP - EPG; int sl = src_gp[i]; s = NP + sl; d = dst_gp[i]; t = 2;
        sc = rsqrtf((float)max(outdeg_gp[sl], 1));
    } else return;
    int pos = row_ptr[d] + atomicAdd(&fill[d], 1);
    payload[pos] = s | (t << 16);
    escale[pos] = sc;
}

// ---------------- pack inputs to padded bf16 ----------------
// job0: x_protein [20000][512] -> xpb [20032][512]; job1: x_go [5000][1000] -> xgb [5056][1024] (k-pad zeroed)
__global__ __launch_bounds__(256) void conv_x_kernel(const float* __restrict__ xp, const float* __restrict__ xg,
                                                     __bf16* __restrict__ xpb, __bf16* __restrict__ xgb)
{
    long long e = ((long long)blockIdx.x * 256 + threadIdx.x) * 8;
    __bf16 pk[8];
    if (blockIdx.y == 0) {
        if (e >= (long long)20032 * 512) return;
        int row = (int)(e >> 9), k = (int)(e & 511);
        if (row < NP) {
            f32x4 v0 = *(const f32x4*)(xp + (size_t)row * 512 + k);
            f32x4 v1 = *(const f32x4*)(xp + (size_t)row * 512 + k + 4);
#pragma unroll
            for (int i = 0; i < 4; i++) { pk[i] = (__bf16)v0[i]; pk[4 + i] = (__bf16)v1[i]; }
        } else {
#pragma unroll
            for (int i = 0; i < 8; i++) pk[i] = (__bf16)0.f;
        }
        *(bf16x8*)(xpb + e) = *(bf16x8*)pk;
    } else {
        if (e >= (long long)5056 * 1024) return;
        int row = (int)(e >> 10), k = (int)(e & 1023);
        if (row < NG && k + 7 < 1000) {
            f32x4 v0 = *(const f32x4*)(xg + (size_t)row * 1000 + k);
            f32x4 v1 = *(const f32x4*)(xg + (size_t)row * 1000 + k + 4);
#pragma unroll
            for (int i = 0; i < 4; i++) { pk[i] = (__bf16)v0[i]; pk[4 + i] = (__bf16)v1[i]; }
        } else {
#pragma unroll
            for (int i = 0; i < 8; i++) {
                int kk = k + i;
                pk[i] = (__bf16)((row < NG && kk < 1000) ? xg[(size_t)row * 1000 + kk] : 0.f);
            }
        }
        *(bf16x8*)(xgb + e) = *(bf16x8*)pk;
    }
}

// ---------------- transpose weights to k-major bf16 [N][K] (padded, zero-filled) ----------------
__global__ __launch_bounds__(256) void conv_w_kernel(
    const float* W1p, const float* W1g, const float* Wlp, const float* Wrp, const float* Wrg,
    const float* Wnl, const float* Wnr, const float* Wfc,
    __bf16* w1pt, __bf16* w1gt, __bf16* wlpt, __bf16* wrpt, __bf16* wrgt,
    __bf16* wnlt, __bf16* wnrt, __bf16* wfct)
{
    int e = blockIdx.x * 256 + threadIdx.x;
    switch (blockIdx.y) {
    case 0: if (e < 128 * 512)  { int n = e >> 9, k = e & 511;  w1pt[e] = (__bf16)W1p[(size_t)k * 128 + n]; } break;
    case 1: if (e < 128 * 1024) { int n = e >> 10, k = e & 1023; w1gt[e] = (__bf16)(k < 1000 ? W1g[(size_t)k * 128 + n] : 0.f); } break;
    case 2: if (e < 16384) { int n = e >> 7, k = e & 127; wlpt[e] = (__bf16)Wlp[(size_t)k * 128 + n]; } break;
    case 3: if (e < 16384) { int n = e >> 7, k = e & 127; wrpt[e] = (__bf16)Wrp[(size_t)k * 128 + n]; } break;
    case 4: if (e < 16384) { int n = e >> 7, k = e & 127; wrgt[e] = (__bf16)Wrg[(size_t)k * 128 + n]; } break;
    case 5: if (e < 16384) { int n = e >> 7, k = e & 127; wnlt[e] = (__bf16)Wnl[(size_t)k * 128 + n]; } break;
    case 6: if (e < 16384) { int n = e >> 7, k = e & 127; wnrt[e] = (__bf16)Wnr[(size_t)k * 128 + n]; } break;
    case 7: if (e < 1024 * 128) { int n = e >> 7, k = e & 127; wfct[e] = (__bf16)(n < 1000 ? Wfc[(size_t)k * 1000 + n] : 0.f); } break;
    }
}

// =====================================================================
// MFMA bf16 GEMM with global_load_lds staging.
// A [Mp][Kp] bf16, B [Np][Kp] bf16 (k-major = W transposed). Tile 64x128, BK=32.
//   ACT: 0 none, 1 ELU, 2 row-l2norm (N==128, gridDim.y==1)
//   DUALA: acc += A2@B2 (bias=b1+b2);  DUALW: O2 = A1@B2 + b2
//   EMIT: 0 -> O1 fp32; 1 -> O1 fp32 + Ob bf16; 2 -> Ob bf16 only
// Two jobs fused per launch via block split.
// =====================================================================
struct GJob {
    const __bf16* A1; const __bf16* A2;
    const __bf16* B1; const __bf16* B2;
    const float* b1; const float* b2;
    float* O1; float* O2; __bf16* Ob;
    int M, N, Kp, ksteps;
};

template<int ACT, int DUALA, int DUALW, int EMIT>
__global__ __launch_bounds__(256) void gemm_bt(GJob j0, GJob j1, int split)
{
    __shared__ __align__(16) __bf16 As[64 * 32];
    __shared__ __align__(16) __bf16 A2s[DUALA ? 64 * 32 : 8];
    __shared__ __align__(16) __bf16 Bs[128 * 32];
    __shared__ __align__(16) __bf16 B2s[(DUALA || DUALW) ? 128 * 32 : 8];
    __shared__ float part[2][64];

    GJob j; int bx;
    if ((int)blockIdx.x < split) { j = j0; bx = blockIdx.x; }
    else { j = j1; bx = blockIdx.x - split; }

    const int tid = threadIdx.x;
    const int wave = tid >> 6, lane = tid & 63;
    const int wr = wave >> 1, wc = wave & 1;
    const int l15 = lane & 15, lh = lane >> 4;
    const int row0 = bx * 64;
    const int col0 = blockIdx.y * 128;

    // staging addresses: thread t -> row=t>>2, k-octet=t&3 (A);  col=t>>2, k-octet=t&3 (B, two col-halves)
    const size_t aoff = (size_t)(row0 + (tid >> 2)) * j.Kp + (tid & 3) * 8;
    const size_t boff0 = (size_t)(col0 + (tid >> 2)) * j.Kp + (tid & 3) * 8;
    const size_t boff1 = boff0 + (size_t)64 * j.Kp;
    char* alds  = (char*)As + wave * 1024;
    char* a2lds = (char*)A2s + wave * 1024;
    char* blds0 = (char*)Bs + wave * 1024;
    char* blds1 = (char*)Bs + 4096 + wave * 1024;
    char* b2lds0 = (char*)B2s + wave * 1024;
    char* b2lds1 = (char*)B2s + 4096 + wave * 1024;

    f32x4 acc[2][4], acc2[2][4];
#pragma unroll
    for (int fm = 0; fm < 2; fm++)
#pragma unroll
        for (int fn = 0; fn < 4; fn++) {
            acc[fm][fn] = (f32x4)0.f;
            if (DUALW) acc2[fm][fn] = (f32x4)0.f;
        }

    for (int ks = 0; ks < j.ksteps; ks++) {
        const int k0 = ks * 32;
        __syncthreads();   // previous iter's LDS consumers done
        gl2lds16(j.A1 + aoff + k0, alds);
        if (DUALA) gl2lds16(j.A2 + aoff + k0, a2lds);
        gl2lds16(j.B1 + boff0 + k0, blds0);
        gl2lds16(j.B1 + boff1 + k0, blds1);
        if (DUALA || DUALW) {
            gl2lds16(j.B2 + boff0 + k0, b2lds0);
            gl2lds16(j.B2 + boff1 + k0, b2lds1);
        }
        __syncthreads();   // drains vmcnt -> LDS visible

#pragma unroll
        for (int fm = 0; fm < 2; fm++) {
            bf16x8 a = *(const bf16x8*)&As[(wr * 32 + fm * 16 + l15) * 32 + lh * 8];
            bf16x8 a2;
            if (DUALA) a2 = *(const bf16x8*)&A2s[(wr * 32 + fm * 16 + l15) * 32 + lh * 8];
#pragma unroll
            for (int fn = 0; fn < 4; fn++) {
                bf16x8 b = *(const bf16x8*)&Bs[(wc * 64 + fn * 16 + l15) * 32 + lh * 8];
                acc[fm][fn] = __builtin_amdgcn_mfma_f32_16x16x32_bf16(a, b, acc[fm][fn], 0, 0, 0);
                if (DUALA) {
                    bf16x8 b2 = *(const bf16x8*)&B2s[(wc * 64 + fn * 16 + l15) * 32 + lh * 8];
                    acc[fm][fn] = __builtin_amdgcn_mfma_f32_16x16x32_bf16(a2, b2, acc[fm][fn], 0, 0, 0);
                }
                if (DUALW) {
                    bf16x8 b2 = *(const bf16x8*)&B2s[(wc * 64 + fn * 16 + l15) * 32 + lh * 8];
                    acc2[fm][fn] = __builtin_amdgcn_mfma_f32_16x16x32_bf16(a, b2, acc2[fm][fn], 0, 0, 0);
                }
            }
        }
    }

    // ---- epilogue ----
    float bias[4], bias2[4];
#pragma unroll
    for (int fn = 0; fn < 4; fn++) {
        int col = col0 + wc * 64 + fn * 16 + l15;
        bias[fn] = 0.f; bias2[fn] = 0.f;
        if (col < j.N) {
            bias[fn] = DUALA ? (j.b1[col] + j.b2[col]) : j.b1[col];
            if (DUALW) bias2[fn] = j.b2[col];
        }
    }

    float vv[2][4][4];
#pragma unroll
    for (int fm = 0; fm < 2; fm++)
#pragma unroll
        for (int fn = 0; fn < 4; fn++)
#pragma unroll
            for (int r = 0; r < 4; r++) {
                float v = acc[fm][fn][r] + bias[fn];
                if (ACT == 1) v = v > 0.f ? v : (expf(v) - 1.f);
                vv[fm][fn][r] = v;
            }

    float scale[2][4];
#pragma unroll
    for (int fm = 0; fm < 2; fm++)
#pragma unroll
        for (int r = 0; r < 4; r++) scale[fm][r] = 1.f;

    if (ACT == 2) {
        float s[2][4];
#pragma unroll
        for (int fm = 0; fm < 2; fm++)
#pragma unroll
            for (int r = 0; r < 4; r++) {
                float v = 0.f;
#pragma unroll
                for (int fn = 0; fn < 4; fn++) v += vv[fm][fn][r] * vv[fm][fn][r];
                v += __shfl_xor(v, 1);
                v += __shfl_xor(v, 2);
                v += __shfl_xor(v, 4);
                v += __shfl_xor(v, 8);
                s[fm][r] = v;
            }
        __syncthreads();
        if (l15 == 0) {
#pragma unroll
            for (int fm = 0; fm < 2; fm++)
#pragma unroll
                for (int r = 0; r < 4; r++)
                    part[wc][wr * 32 + fm * 16 + lh * 4 + r] = s[fm][r];
        }
        __syncthreads();
#pragma unroll
        for (int fm = 0; fm < 2; fm++)
#pragma unroll
            for (int r = 0; r < 4; r++) {
                int rl = wr * 32 + fm * 16 + lh * 4 + r;
                float ss = part[0][rl] + part[1][rl];
                scale[fm][r] = 1.f / fmaxf(sqrtf(ss), 1e-12f);
            }
    }

#pragma unroll
    for (int fm = 0; fm < 2; fm++)
#pragma unroll
        for (int fn = 0; fn < 4; fn++)
#pragma unroll
            for (int r = 0; r < 4; r++) {
                int row = row0 + wr * 32 + fm * 16 + lh * 4 + r;
                int col = col0 + wc * 64 + fn * 16 + l15;
                if (row < j.M && col < j.N) {
                    float v = vv[fm][fn][r] * scale[fm][r];
                    if (EMIT != 2) j.O1[(size_t)row * j.N + col] = v;
                    if (EMIT != 0) j.Ob[(size_t)row * j.N + col] = (__bf16)v;
                    if (DUALW) j.O2[(size_t)row * j.N + col] = acc2[fm][fn][r] + bias2[fn];
                }
            }
}

// ---------------- GCN aggregation onto protein dst nodes (bf16 out) ----------------
template<typename XT>
__global__ __launch_bounds__(128) void rst_agg_kernel(const XT* __restrict__ x,
                                                      const int* __restrict__ row_ptr,
                                                      const int* __restrict__ payload,
                                                      const float* __restrict__ escale,
                                                      const int* __restrict__ indeg_pp,
                                                      const int* __restrict__ indeg_gp,
                                                      __bf16* __restrict__ rppb, __bf16* __restrict__ rgpb)
{
    int d = blockIdx.x;  // < NP
    int c = threadIdx.x;
    int beg = row_ptr[d], end = row_ptr[d + 1];
    float spp = 0.f, sgp = 0.f;
    __shared__ int pl[128];
    __shared__ float sc[128];
    for (int base = beg; base < end; base += 128) {
        int n = min(128, end - base);
        __syncthreads();
        if (c < n) { pl[c] = payload[base + c]; sc[c] = escale[base + c]; }
        __syncthreads();
        for (int i = 0; i < n; i++) {
            int p = pl[i]; int s = p & 0xFFFF; int t = p >> 16;
            float v = (float)x[(size_t)s * DH + c] * sc[i];
            if (t == 0) spp += v; else sgp += v;
        }
    }
    float ipp = rsqrtf((float)max(indeg_pp[d], 1));
    float igp = rsqrtf((float)max(indeg_gp[d], 1));
    rppb[(size_t)d * DH + c] = (__bf16)(spp * ipp);
    rgpb[(size_t)d * DH + c] = (__bf16)(sgp * igp);
}

// ---------------- per-(protein,channel) type-level alpha weights, in-place ----------------
__global__ void wa_kernel(const int* __restrict__ indeg_pp, const int* __restrict__ indeg_gp,
                          float* __restrict__ eapp, float* __restrict__ eagp)
{
    int idx = blockIdx.x * blockDim.x + threadIdx.x;
    if (idx >= NP * DH) return;
    int d = idx >> 7;
    int npp = indeg_pp[d], ngp = indeg_gp[d];
    float app = eapp[idx], agp = eagp[idx];
    float wpp = 0.f, wgp = 0.f;
    if (npp > 0 && ngp > 0) {
        float mx = fmaxf(app, agp);
        float epp = expf(app - mx), egp = expf(agp - mx);
        float den = (float)npp * epp + (float)ngp * egp;
        wpp = epp / den; wgp = egp / den;
    } else if (npp > 0) wpp = 1.f / (float)npp;
    else if (ngp > 0) wgp = 1.f / (float)ngp;
    eapp[idx] = wpp;
    eagp[idx] = wgp;
}

// ---------------- node attention: online softmax over incoming edges + aggregation ----------------
template<typename XT>
__global__ __launch_bounds__(128) void node_attn_kernel(const XT* __restrict__ x,
                                                        const float* __restrict__ hl, const float* __restrict__ hr,
                                                        const float* __restrict__ wpp_arr, const float* __restrict__ wgp_arr,
                                                        const int* __restrict__ indeg_pg,
                                                        const int* __restrict__ row_ptr, const int* __restrict__ payload,
                                                        __bf16* __restrict__ hb)
{
    int d = blockIdx.x, c = threadIdx.x;
    int beg = row_ptr[d], end = row_ptr[d + 1];
    float hrd = hr[(size_t)d * DH + c];
    float wpp = 0.f, wgp = 0.f, wpg = 0.f;
    if (d < NP) {
        wpp = wpp_arr[(size_t)d * DH + c];
        wgp = wgp_arr[(size_t)d * DH + c];
    } else {
        wpg = 1.f / (float)max(indeg_pg[d - NP], 1);
    }
    float m = -INFINITY, ssum = 0.f, acc = 0.f;
    __shared__ int pl[128];
    for (int base = beg; base < end; base += 128) {
        int n = min(128, end - base);
        __syncthreads();
        if (c < n) pl[c] = payload[base + c];
        __syncthreads();
        for (int i = 0; i < n; i++) {
            int p = pl[i]; int s = p & 0xFFFF; int t = p >> 16;
            float al = (d < NP) ? (t == 0 ? wpp : wgp) : wpg;
            float e = (hl[(size_t)s * DH + c] + hrd) * al;
            e = e > 0.f ? e : -0.2f * e;   // LeakyReLU slope = -0.2
            float xv = (float)x[(size_t)s * DH + c];
            if (e > m) {
                float r0 = expf(m - e);
                ssum = ssum * r0 + 1.f;
                acc = acc * r0 + xv;
                m = e;
            } else {
                float p2 = expf(e - m);
                ssum += p2;
                acc += p2 * xv;
            }
        }
    }
    hb[(size_t)d * DH + c] = (__bf16)((end > beg) ? acc / ssum : 0.f);
}

extern "C" void kernel_launch(void* const* d_in, const int* in_sizes, int n_in,
                              void* d_out, int out_size, void* d_ws, size_t ws_size,
                              hipStream_t stream)
{
    const float* x_protein = (const float*)d_in[0];
    const float* x_go      = (const float*)d_in[1];
    const int* src_pp = (const int*)d_in[2];
    const int* dst_pp = (const int*)d_in[3];
    const int* src_pg = (const int*)d_in[4];
    const int* dst_pg = (const int*)d_in[5];
    const int* src_gp = (const int*)d_in[6];
    const int* dst_gp = (const int*)d_in[7];
    const float* W1p = (const float*)d_in[8];
    const float* b1p = (const float*)d_in[9];
    const float* W1g = (const float*)d_in[10];
    const float* b1g = (const float*)d_in[11];
    const float* Wl_p = (const float*)d_in[12];
    const float* bl_p = (const float*)d_in[13];
    // Wl_g (14), bl_g (15) dead: go-dst type-alpha is uniform 1/n
    const float* Wr_p = (const float*)d_in[16];
    const float* br_p = (const float*)d_in[17];
    const float* Wr_g = (const float*)d_in[18];
    const float* br_g = (const float*)d_in[19];
    const float* Wnl = (const float*)d_in[20];
    const float* bnl = (const float*)d_in[21];
    const float* Wnr = (const float*)d_in[22];
    const float* bnr = (const float*)d_in[23];
    const float* Wfc = (const float*)d_in[24];
    const float* bfc = (const float*)d_in[25];
    float* out = (float*)d_out;

    // ---- workspace layout (word = 4B units, 16B-aligned blocks) ----
    size_t off = 0;
    char* base = (char*)d_ws;
    auto alloc = [&](size_t words) { void* p = base + off * 4; off += (words + 7) & ~(size_t)7; return p; };

    __bf16* xb   = (__bf16*)alloc((size_t)25024 * 128 / 2);
    float*  hl   = (float*)alloc((size_t)25000 * 128);
    float*  hr   = (float*)alloc((size_t)25000 * 128);
    __bf16* rppb = (__bf16*)alloc((size_t)20032 * 128 / 2);
    __bf16* rgpb = (__bf16*)alloc((size_t)20032 * 128 / 2);
    // R1: xpb+xgb during proj; wpp,wgp,haggb after
    char* R1 = (char*)alloc((size_t)5128192 + 2588672);
    __bf16* xpb = (__bf16*)R1;                             // 20032*512
    __bf16* xgb = (__bf16*)(R1 + (size_t)20032 * 512 * 2); // 5056*1024
    float*  wpp = (float*)R1;                              // 20000*128
    float*  wgp = wpp + (size_t)20000 * 128;
    __bf16* haggb = (__bf16*)(wgp + (size_t)20000 * 128);  // 25024*128
    __bf16* w1pt = (__bf16*)alloc(128 * 512 / 2);
    __bf16* w1gt = (__bf16*)alloc(128 * 1024 / 2);
    __bf16* wlpt = (__bf16*)alloc(128 * 128 / 2);
    __bf16* wrpt = (__bf16*)alloc(128 * 128 / 2);
    __bf16* wrgt = (__bf16*)alloc(128 * 128 / 2);
    __bf16* wnlt = (__bf16*)alloc(128 * 128 / 2);
    __bf16* wnrt = (__bf16*)alloc(128 * 128 / 2);
    __bf16* wfct = (__bf16*)alloc(1024 * 128 / 2);
    int* ibase = (int*)alloc(140000 + 25001 + 440000);
    int* outdeg_pp = ibase;
    int* outdeg_pg = outdeg_pp + NP;
    int* outdeg_gp = outdeg_pg + NP;
    int* indeg_pp  = outdeg_gp + NG;
    int* indeg_gp  = indeg_pp + NP;
    int* indeg_pg  = indeg_gp + NP;
    int* cnt       = indeg_pg + NG;
    int* fill      = cnt + NTOT;
    int* row_ptr   = fill + NTOT;
    int* payload   = row_ptr + NTOT + 1;
    float* escale  = (float*)alloc(440000);
    float* xf      = (float*)alloc((size_t)25000 * 128);   // optional fp32 x for gathers
    const bool use_f32x = (ws_size >= off * 4);

    hipMemsetAsync(ibase, 0, (size_t)140000 * sizeof(int), stream);

    const int EB = (ETOT + 255) / 256;
    hist_kernel<<<EB, 256, 0, stream>>>(src_pp, dst_pp, src_pg, dst_pg, src_gp, dst_gp,
                                        outdeg_pp, outdeg_pg, outdeg_gp,
                                        indeg_pp, indeg_gp, indeg_pg, cnt);
    scan_kernel<<<1, 1024, 0, stream>>>(cnt, row_ptr);
    scatter_kernel<<<EB, 256, 0, stream>>>(src_pp, dst_pp, src_pg, dst_pg, src_gp, dst_gp,
                                           outdeg_pp, outdeg_pg, outdeg_gp,
                                           row_ptr, fill, payload, escale);

    conv_x_kernel<<<dim3(5008, 2), 256, 0, stream>>>(x_protein, x_go, xpb, xgb);
    conv_w_kernel<<<dim3(512, 8), 256, 0, stream>>>(W1p, W1g, Wl_p, Wr_p, Wr_g, Wnl, Wnr, Wfc,
                                                    w1pt, w1gt, wlpt, wrpt, wrgt, wnlt, wnrt, wfct);

    // fused projections + l2norm: blocks [0,313) protein, [313,392) go
    {
        GJob p0 = { xpb, nullptr, w1pt, nullptr, b1p, nullptr, xf, nullptr, xb, NP, 128, 512, 16 };
        GJob p1 = { xgb, nullptr, w1gt, nullptr, b1g, nullptr, xf + (size_t)NP * 128, nullptr,
                    xb + (size_t)NP * 128, NG, 128, 1024, 32 };
        if (use_f32x) gemm_bt<2, 0, 0, 1><<<392, 256, 0, stream>>>(p0, p1, 313);
        else          gemm_bt<2, 0, 0, 2><<<392, 256, 0, stream>>>(p0, p1, 313);
    }

    // GCN aggregation for type attention (protein dst only)
    if (use_f32x)
        rst_agg_kernel<float><<<NP, 128, 0, stream>>>(xf, row_ptr, payload, escale, indeg_pp, indeg_gp, rppb, rgpb);
    else
        rst_agg_kernel<__bf16><<<NP, 128, 0, stream>>>(xb, row_ptr, payload, escale, indeg_pp, indeg_gp, rppb, rgpb);

    // fused ea: wpp = elu(x@Wl_p + rpp@Wr_p + bl_p+br_p); wgp = elu(x@Wl_p + rgp@Wr_g + bl_p+br_g)
    {
        GJob e0 = { xb, rppb, wlpt, wrpt, bl_p, br_p, wpp, nullptr, nullptr, NP, 128, 128, 4 };
        GJob e1 = { xb, rgpb, wlpt, wrgt, bl_p, br_g, wgp, nullptr, nullptr, NP, 128, 128, 4 };
        gemm_bt<1, 1, 0, 0><<<626, 256, 0, stream>>>(e0, e1, 313);
    }

    // type-level alpha weights (in-place over wpp/wgp)
    wa_kernel<<<(NP * DH + 255) / 256, 256, 0, stream>>>(indeg_pp, indeg_gp, wpp, wgp);

    // node attention projections: hl = x@Wnl+bnl, hr = x@Wnr+bnr
    {
        GJob h0 = { xb, nullptr, wnlt, wnrt, bnl, bnr, hl, hr, nullptr, NTOT, 128, 128, 4 };
        gemm_bt<0, 0, 1, 0><<<391, 256, 0, stream>>>(h0, h0, 1 << 30);
    }

    // node attention + aggregation -> haggb (bf16)
    if (use_f32x)
        node_attn_kernel<float><<<NTOT, 128, 0, stream>>>(xf, hl, hr, wpp, wgp, indeg_pg, row_ptr, payload, haggb);
    else
        node_attn_kernel<__bf16><<<NTOT, 128, 0, stream>>>(xb, hl, hr, wpp, wgp, indeg_pg, row_ptr, payload, haggb);

    // final classifier: out = hagg@Wfc + bfc
    {
        GJob o0 = { haggb, nullptr, wfct, nullptr, bfc, nullptr, out, nullptr, nullptr, NTOT, NCLS, 128, 4 };
        gemm_bt<0, 0, 0, 0><<<dim3(391, 8), 256, 0, stream>>>(o0, o0, 1 << 30);
    }

    (void)in_sizes; (void)n_in; (void)out_size; (void)ws_size;
}

// Round 4
// 296.395 us; speedup vs baseline: 2.8201x; 1.1650x over previous
//
#include <hip/hip_runtime.h>
#include <math.h>

#define NP 20000
#define NG 5000
#define NTOT 25000
#define DF 512
#define NCLS 1000
#define DH 128
#define EPP 240000
#define EPG 100000
#define EGP 100000
#define ETOT 440000

typedef __attribute__((ext_vector_type(8))) __bf16 bf16x8;
typedef __attribute__((ext_vector_type(4))) float f32x4;

// async global->LDS, 16B per lane; LDS dest = wave-uniform base + lane*16
__device__ __forceinline__ void gl2lds16(const void* g, void* l) {
    __builtin_amdgcn_global_load_lds(
        (const __attribute__((address_space(1))) unsigned int*)g,
        (__attribute__((address_space(3))) unsigned int*)l, 16, 0, 0);
}

__device__ __forceinline__ float b2f(unsigned short u) {
    union { unsigned int i; float f; } c; c.i = ((unsigned int)u) << 16; return c.f;
}

// ---------------- histogram of degrees + homogeneous dst counts ----------------
__global__ void hist_kernel(const int* __restrict__ src_pp, const int* __restrict__ dst_pp,
                            const int* __restrict__ src_pg, const int* __restrict__ dst_pg,
                            const int* __restrict__ src_gp, const int* __restrict__ dst_gp,
                            int* outdeg_pp, int* outdeg_pg, int* outdeg_gp,
                            int* indeg_pp, int* indeg_gp, int* indeg_pg,
                            int* cnt)
{
    int e = blockIdx.x * blockDim.x + threadIdx.x;
    if (e < EPP) {
        int s = src_pp[e], d = dst_pp[e];
        atomicAdd(&outdeg_pp[s], 1); atomicAdd(&indeg_pp[d], 1); atomicAdd(&cnt[d], 1);
    } else if (e < EPP + EPG) {
        int i = e - EPP; int s = src_pg[i], d = dst_pg[i];
        atomicAdd(&outdeg_pg[s], 1); atomicAdd(&indeg_pg[d], 1); atomicAdd(&cnt[NP + d], 1);
    } else if (e < ETOT) {
        int i = e - EPP - EPG; int s = src_gp[i], d = dst_gp[i];
        atomicAdd(&outdeg_gp[s], 1); atomicAdd(&indeg_gp[d], 1); atomicAdd(&cnt[d], 1);
    }
}

// ---------------- exclusive scan of cnt[NTOT] -> row_ptr[NTOT+1] ----------------
__global__ __launch_bounds__(1024) void scan_kernel(const int* __restrict__ cnt, int* __restrict__ row_ptr)
{
    __shared__ int part[1024];
    int t = threadIdx.x;
    const int CH = (NTOT + 1023) / 1024;  // 25
    int base = t * CH;
    int s = 0;
    for (int i = 0; i < CH; i++) { int idx = base + i; if (idx < NTOT) s += cnt[idx]; }
    part[t] = s;
    __syncthreads();
    for (int off = 1; off < 1024; off <<= 1) {
        int v = (t >= off) ? part[t - off] : 0;
        __syncthreads();
        part[t] += v;
        __syncthreads();
    }
    int run = (t == 0) ? 0 : part[t - 1];
    for (int i = 0; i < CH; i++) {
        int idx = base + i;
        if (idx < NTOT) { row_ptr[idx] = run; run += cnt[idx]; }
    }
    if (t == 1023) row_ptr[NTOT] = part[1023];
}

// ---------------- scatter edges into CSR ----------------
__global__ void scatter_kernel(const int* __restrict__ src_pp, const int* __restrict__ dst_pp,
                               const int* __restrict__ src_pg, const int* __restrict__ dst_pg,
                               const int* __restrict__ src_gp, const int* __restrict__ dst_gp,
                               const int* __restrict__ outdeg_pp, const int* __restrict__ outdeg_pg,
                               const int* __restrict__ outdeg_gp,
                               const int* __restrict__ row_ptr, int* fill,
                               int* __restrict__ payload, float* __restrict__ escale)
{
    int e = blockIdx.x * blockDim.x + threadIdx.x;
    int s, d, t; float sc;
    if (e < EPP) {
        s = src_pp[e]; d = dst_pp[e]; t = 0;
        sc = rsqrtf((float)max(outdeg_pp[s], 1));
    } else if (e < EPP + EPG) {
        int i = e - EPP; s = src_pg[i]; d = NP + dst_pg[i]; t = 1;
        sc = rsqrtf((float)max(outdeg_pg[s], 1));
    } else if (e < ETOT) {
        int i = e - EPP - EPG; int sl = src_gp[i]; s = NP + sl; d = dst_gp[i]; t = 2;
        sc = rsqrtf((float)max(outdeg_gp[sl], 1));
    } else return;
    int pos = row_ptr[d] + atomicAdd(&fill[d], 1);
    payload[pos] = s | (t << 16);
    escale[pos] = sc;
}

// ---------------- pack inputs to padded bf16 ----------------
__global__ __launch_bounds__(256) void conv_x_kernel(const float* __restrict__ xp, const float* __restrict__ xg,
                                                     __bf16* __restrict__ xpb, __bf16* __restrict__ xgb)
{
    long long e = ((long long)blockIdx.x * 256 + threadIdx.x) * 8;
    __bf16 pk[8];
    if (blockIdx.y == 0) {
        if (e >= (long long)20032 * 512) return;
        int row = (int)(e >> 9), k = (int)(e & 511);
        if (row < NP) {
            f32x4 v0 = *(const f32x4*)(xp + (size_t)row * 512 + k);
            f32x4 v1 = *(const f32x4*)(xp + (size_t)row * 512 + k + 4);
#pragma unroll
            for (int i = 0; i < 4; i++) { pk[i] = (__bf16)v0[i]; pk[4 + i] = (__bf16)v1[i]; }
        } else {
#pragma unroll
            for (int i = 0; i < 8; i++) pk[i] = (__bf16)0.f;
        }
        *(bf16x8*)(xpb + e) = *(bf16x8*)pk;
    } else {
        if (e >= (long long)5056 * 1024) return;
        int row = (int)(e >> 10), k = (int)(e & 1023);
        if (row < NG && k + 7 < 1000) {
            f32x4 v0 = *(const f32x4*)(xg + (size_t)row * 1000 + k);
            f32x4 v1 = *(const f32x4*)(xg + (size_t)row * 1000 + k + 4);
#pragma unroll
            for (int i = 0; i < 4; i++) { pk[i] = (__bf16)v0[i]; pk[4 + i] = (__bf16)v1[i]; }
        } else {
#pragma unroll
            for (int i = 0; i < 8; i++) {
                int kk = k + i;
                pk[i] = (__bf16)((row < NG && kk < 1000) ? xg[(size_t)row * 1000 + kk] : 0.f);
            }
        }
        *(bf16x8*)(xgb + e) = *(bf16x8*)pk;
    }
}

// ---------------- transpose weights to k-major bf16 [N][K] (padded, zero-filled) ----------------
__global__ __launch_bounds__(256) void conv_w_kernel(
    const float* W1p, const float* W1g, const float* Wlp, const float* Wrp, const float* Wrg,
    const float* Wnl, const float* Wnr, const float* Wfc,
    __bf16* w1pt, __bf16* w1gt, __bf16* wlpt, __bf16* wrpt, __bf16* wrgt,
    __bf16* wnlt, __bf16* wnrt, __bf16* wfct)
{
    int e = blockIdx.x * 256 + threadIdx.x;
    switch (blockIdx.y) {
    case 0: if (e < 128 * 512)  { int n = e >> 9, k = e & 511;  w1pt[e] = (__bf16)W1p[(size_t)k * 128 + n]; } break;
    case 1: if (e < 128 * 1024) { int n = e >> 10, k = e & 1023; w1gt[e] = (__bf16)(k < 1000 ? W1g[(size_t)k * 128 + n] : 0.f); } break;
    case 2: if (e < 16384) { int n = e >> 7, k = e & 127; wlpt[e] = (__bf16)Wlp[(size_t)k * 128 + n]; } break;
    case 3: if (e < 16384) { int n = e >> 7, k = e & 127; wrpt[e] = (__bf16)Wrp[(size_t)k * 128 + n]; } break;
    case 4: if (e < 16384) { int n = e >> 7, k = e & 127; wrgt[e] = (__bf16)Wrg[(size_t)k * 128 + n]; } break;
    case 5: if (e < 16384) { int n = e >> 7, k = e & 127; wnlt[e] = (__bf16)Wnl[(size_t)k * 128 + n]; } break;
    case 6: if (e < 16384) { int n = e >> 7, k = e & 127; wnrt[e] = (__bf16)Wnr[(size_t)k * 128 + n]; } break;
    case 7: if (e < 1024 * 128) { int n = e >> 7, k = e & 127; wfct[e] = (__bf16)(n < 1000 ? Wfc[(size_t)k * 1000 + n] : 0.f); } break;
    }
}

// =====================================================================
// MFMA bf16 GEMM with global_load_lds staging (m97 structure).
//   ACT: 0 none, 1 ELU, 2 row-l2norm (N==128, gridDim.y==1)
//   DUALA: acc += A2@B2 (bias=b1+b2);  DUALW: O2 = A1@B2 + b2 (fp32)
//   EMIT: 0 -> O1 fp32; 1 -> O1 fp32 + Ob bf16; 2 -> Ob bf16 only
// =====================================================================
struct GJob {
    const __bf16* A1; const __bf16* A2;
    const __bf16* B1; const __bf16* B2;
    const float* b1; const float* b2;
    float* O1; float* O2; __bf16* Ob;
    int M, N, Kp, ksteps;
};

template<int ACT, int DUALA, int DUALW, int EMIT>
__global__ __launch_bounds__(256) void gemm_bt(GJob j0, GJob j1, int split)
{
    __shared__ __align__(16) __bf16 As[64 * 32];
    __shared__ __align__(16) __bf16 A2s[DUALA ? 64 * 32 : 8];
    __shared__ __align__(16) __bf16 Bs[128 * 32];
    __shared__ __align__(16) __bf16 B2s[(DUALA || DUALW) ? 128 * 32 : 8];
    __shared__ float part[2][64];

    GJob j; int bx;
    if ((int)blockIdx.x < split) { j = j0; bx = blockIdx.x; }
    else { j = j1; bx = blockIdx.x - split; }

    const int tid = threadIdx.x;
    const int wave = tid >> 6, lane = tid & 63;
    const int wr = wave >> 1, wc = wave & 1;
    const int l15 = lane & 15, lh = lane >> 4;
    const int row0 = bx * 64;
    const int col0 = blockIdx.y * 128;

    const size_t aoff = (size_t)(row0 + (tid >> 2)) * j.Kp + (tid & 3) * 8;
    const size_t boff0 = (size_t)(col0 + (tid >> 2)) * j.Kp + (tid & 3) * 8;
    const size_t boff1 = boff0 + (size_t)64 * j.Kp;
    char* alds  = (char*)As + wave * 1024;
    char* a2lds = (char*)A2s + wave * 1024;
    char* blds0 = (char*)Bs + wave * 1024;
    char* blds1 = (char*)Bs + 4096 + wave * 1024;
    char* b2lds0 = (char*)B2s + wave * 1024;
    char* b2lds1 = (char*)B2s + 4096 + wave * 1024;

    f32x4 acc[2][4], acc2[2][4];
#pragma unroll
    for (int fm = 0; fm < 2; fm++)
#pragma unroll
        for (int fn = 0; fn < 4; fn++) {
            acc[fm][fn] = (f32x4)0.f;
            if (DUALW) acc2[fm][fn] = (f32x4)0.f;
        }

    for (int ks = 0; ks < j.ksteps; ks++) {
        const int k0 = ks * 32;
        __syncthreads();
        gl2lds16(j.A1 + aoff + k0, alds);
        if (DUALA) gl2lds16(j.A2 + aoff + k0, a2lds);
        gl2lds16(j.B1 + boff0 + k0, blds0);
        gl2lds16(j.B1 + boff1 + k0, blds1);
        if (DUALA || DUALW) {
            gl2lds16(j.B2 + boff0 + k0, b2lds0);
            gl2lds16(j.B2 + boff1 + k0, b2lds1);
        }
        __syncthreads();

#pragma unroll
        for (int fm = 0; fm < 2; fm++) {
            bf16x8 a = *(const bf16x8*)&As[(wr * 32 + fm * 16 + l15) * 32 + lh * 8];
            bf16x8 a2;
            if (DUALA) a2 = *(const bf16x8*)&A2s[(wr * 32 + fm * 16 + l15) * 32 + lh * 8];
#pragma unroll
            for (int fn = 0; fn < 4; fn++) {
                bf16x8 b = *(const bf16x8*)&Bs[(wc * 64 + fn * 16 + l15) * 32 + lh * 8];
                acc[fm][fn] = __builtin_amdgcn_mfma_f32_16x16x32_bf16(a, b, acc[fm][fn], 0, 0, 0);
                if (DUALA) {
                    bf16x8 b2 = *(const bf16x8*)&B2s[(wc * 64 + fn * 16 + l15) * 32 + lh * 8];
                    acc[fm][fn] = __builtin_amdgcn_mfma_f32_16x16x32_bf16(a2, b2, acc[fm][fn], 0, 0, 0);
                }
                if (DUALW) {
                    bf16x8 b2 = *(const bf16x8*)&B2s[(wc * 64 + fn * 16 + l15) * 32 + lh * 8];
                    acc2[fm][fn] = __builtin_amdgcn_mfma_f32_16x16x32_bf16(a, b2, acc2[fm][fn], 0, 0, 0);
                }
            }
        }
    }

    // ---- epilogue ----
    float bias[4], bias2[4];
#pragma unroll
    for (int fn = 0; fn < 4; fn++) {
        int col = col0 + wc * 64 + fn * 16 + l15;
        bias[fn] = 0.f; bias2[fn] = 0.f;
        if (col < j.N) {
            bias[fn] = DUALA ? (j.b1[col] + j.b2[col]) : j.b1[col];
            if (DUALW) bias2[fn] = j.b2[col];
        }
    }

    float vv[2][4][4];
#pragma unroll
    for (int fm = 0; fm < 2; fm++)
#pragma unroll
        for (int fn = 0; fn < 4; fn++)
#pragma unroll
            for (int r = 0; r < 4; r++) {
                float v = acc[fm][fn][r] + bias[fn];
                if (ACT == 1) v = v > 0.f ? v : (expf(v) - 1.f);
                vv[fm][fn][r] = v;
            }

    float scale[2][4];
#pragma unroll
    for (int fm = 0; fm < 2; fm++)
#pragma unroll
        for (int r = 0; r < 4; r++) scale[fm][r] = 1.f;

    if (ACT == 2) {
        float s[2][4];
#pragma unroll
        for (int fm = 0; fm < 2; fm++)
#pragma unroll
            for (int r = 0; r < 4; r++) {
                float v = 0.f;
#pragma unroll
                for (int fn = 0; fn < 4; fn++) v += vv[fm][fn][r] * vv[fm][fn][r];
                v += __shfl_xor(v, 1);
                v += __shfl_xor(v, 2);
                v += __shfl_xor(v, 4);
                v += __shfl_xor(v, 8);
                s[fm][r] = v;
            }
        __syncthreads();
        if (l15 == 0) {
#pragma unroll
            for (int fm = 0; fm < 2; fm++)
#pragma unroll
                for (int r = 0; r < 4; r++)
                    part[wc][wr * 32 + fm * 16 + lh * 4 + r] = s[fm][r];
        }
        __syncthreads();
#pragma unroll
        for (int fm = 0; fm < 2; fm++)
#pragma unroll
            for (int r = 0; r < 4; r++) {
                int rl = wr * 32 + fm * 16 + lh * 4 + r;
                float ss = part[0][rl] + part[1][rl];
                scale[fm][r] = 1.f / fmaxf(sqrtf(ss), 1e-12f);
            }
    }

#pragma unroll
    for (int fm = 0; fm < 2; fm++)
#pragma unroll
        for (int fn = 0; fn < 4; fn++)
#pragma unroll
            for (int r = 0; r < 4; r++) {
                int row = row0 + wr * 32 + fm * 16 + lh * 4 + r;
                int col = col0 + wc * 64 + fn * 16 + l15;
                if (row < j.M && col < j.N) {
                    float v = vv[fm][fn][r] * scale[fm][r];
                    if (EMIT != 2) j.O1[(size_t)row * j.N + col] = v;
                    if (EMIT != 0) j.Ob[(size_t)row * j.N + col] = (__bf16)v;
                    if (DUALW) j.O2[(size_t)row * j.N + col] = acc2[fm][fn][r] + bias2[fn];
                }
            }
}

// ---------------- GCN aggregation onto protein dst nodes (bf16 gather, bf16 out) ----------------
__global__ __launch_bounds__(128) void rst_agg_kernel(const __bf16* __restrict__ x,
                                                      const int* __restrict__ row_ptr,
                                                      const int* __restrict__ payload,
                                                      const float* __restrict__ escale,
                                                      const int* __restrict__ indeg_pp,
                                                      const int* __restrict__ indeg_gp,
                                                      __bf16* __restrict__ rppb, __bf16* __restrict__ rgpb)
{
    int d = blockIdx.x;  // < NP
    int c = threadIdx.x;
    int beg = row_ptr[d], end = row_ptr[d + 1];
    float spp = 0.f, sgp = 0.f;
    __shared__ int pl[128];
    __shared__ float sc[128];
    const unsigned short* xu = (const unsigned short*)x;
    for (int base = beg; base < end; base += 128) {
        int n = min(128, end - base);
        __syncthreads();
        if (c < n) { pl[c] = payload[base + c]; sc[c] = escale[base + c]; }
        __syncthreads();
        for (int i = 0; i < n; i++) {
            int p = pl[i]; int s = p & 0xFFFF; int t = p >> 16;
            float v = b2f(xu[(size_t)s * DH + c]) * sc[i];
            if (t == 0) spp += v; else sgp += v;
        }
    }
    float ipp = rsqrtf((float)max(indeg_pp[d], 1));
    float igp = rsqrtf((float)max(indeg_gp[d], 1));
    rppb[(size_t)d * DH + c] = (__bf16)(spp * ipp);
    rgpb[(size_t)d * DH + c] = (__bf16)(sgp * igp);
}

// ---------------- per-(protein,channel) type-level alpha weights, in-place ----------------
__global__ void wa_kernel(const int* __restrict__ indeg_pp, const int* __restrict__ indeg_gp,
                          float* __restrict__ eapp, float* __restrict__ eagp)
{
    int idx = blockIdx.x * blockDim.x + threadIdx.x;
    if (idx >= NP * DH) return;
    int d = idx >> 7;
    int npp = indeg_pp[d], ngp = indeg_gp[d];
    float app = eapp[idx], agp = eagp[idx];
    float wpp = 0.f, wgp = 0.f;
    if (npp > 0 && ngp > 0) {
        float mx = fmaxf(app, agp);
        float epp = __expf(app - mx), egp = __expf(agp - mx);
        float den = (float)npp * epp + (float)ngp * egp;
        wpp = epp / den; wgp = egp / den;
    } else if (npp > 0) wpp = 1.f / (float)npp;
    else if (ngp > 0) wgp = 1.f / (float)ngp;
    eapp[idx] = wpp;
    eagp[idx] = wgp;
}

// ---------------- node attention: branchless softmax (no max shift; |e| <= ~2) ----------------
__global__ __launch_bounds__(128) void node_attn_kernel(const __bf16* __restrict__ x,
                                                        const __bf16* __restrict__ hlb,
                                                        const float* __restrict__ hr,
                                                        const float* __restrict__ wpp_arr, const float* __restrict__ wgp_arr,
                                                        const int* __restrict__ indeg_pg,
                                                        const int* __restrict__ row_ptr, const int* __restrict__ payload,
                                                        __bf16* __restrict__ hb)
{
    int d = blockIdx.x, c = threadIdx.x;
    int beg = row_ptr[d], end = row_ptr[d + 1];
    float hrd = hr[(size_t)d * DH + c];
    float wpp = 0.f, wgp = 0.f;
    if (d < NP) {
        wpp = wpp_arr[(size_t)d * DH + c];
        wgp = wgp_arr[(size_t)d * DH + c];
    } else {
        float wpg = 1.f / (float)max(indeg_pg[d - NP], 1);
        wpp = wpg; wgp = wpg;
    }
    float ssum = 0.f, acc = 0.f;
    __shared__ int pl[128];
    const unsigned short* xu = (const unsigned short*)x;
    const unsigned short* hu = (const unsigned short*)hlb;
    for (int base = beg; base < end; base += 128) {
        int n = min(128, end - base);
        __syncthreads();
        if (c < n) pl[c] = payload[base + c];
        __syncthreads();
        for (int i = 0; i < n; i++) {
            int p = pl[i]; int s = p & 0xFFFF; int t = p >> 16;
            float al = (t == 0) ? wpp : wgp;   // pp vs {gp,pg}; go-dst: both equal wpg
            float e = (b2f(hu[(size_t)s * DH + c]) + hrd) * al;
            e = fmaxf(e, -0.2f * e);           // LeakyReLU slope -0.2
            float pw = __expf(e);
            float xv = b2f(xu[(size_t)s * DH + c]);
            ssum += pw;
            acc += pw * xv;
        }
    }
    hb[(size_t)d * DH + c] = (__bf16)((end > beg) ? acc / ssum : 0.f);
}

extern "C" void kernel_launch(void* const* d_in, const int* in_sizes, int n_in,
                              void* d_out, int out_size, void* d_ws, size_t ws_size,
                              hipStream_t stream)
{
    const float* x_protein = (const float*)d_in[0];
    const float* x_go      = (const float*)d_in[1];
    const int* src_pp = (const int*)d_in[2];
    const int* dst_pp = (const int*)d_in[3];
    const int* src_pg = (const int*)d_in[4];
    const int* dst_pg = (const int*)d_in[5];
    const int* src_gp = (const int*)d_in[6];
    const int* dst_gp = (const int*)d_in[7];
    const float* W1p = (const float*)d_in[8];
    const float* b1p = (const float*)d_in[9];
    const float* W1g = (const float*)d_in[10];
    const float* b1g = (const float*)d_in[11];
    const float* Wl_p = (const float*)d_in[12];
    const float* bl_p = (const float*)d_in[13];
    // Wl_g (14), bl_g (15) dead: go-dst type-alpha is uniform 1/n
    const float* Wr_p = (const float*)d_in[16];
    const float* br_p = (const float*)d_in[17];
    const float* Wr_g = (const float*)d_in[18];
    const float* br_g = (const float*)d_in[19];
    const float* Wnl = (const float*)d_in[20];
    const float* bnl = (const float*)d_in[21];
    const float* Wnr = (const float*)d_in[22];
    const float* bnr = (const float*)d_in[23];
    const float* Wfc = (const float*)d_in[24];
    const float* bfc = (const float*)d_in[25];
    float* out = (float*)d_out;

    // ---- workspace layout (4B words, 16B-aligned blocks); total ~72 MB ----
    size_t off = 0;
    char* base = (char*)d_ws;
    auto alloc = [&](size_t words) { void* p = base + off * 4; off += (words + 7) & ~(size_t)7; return p; };

    __bf16* xb   = (__bf16*)alloc((size_t)25024 * 128 / 2);
    float*  hr   = (float*)alloc((size_t)25000 * 128);
    __bf16* hlb  = (__bf16*)alloc((size_t)25024 * 128 / 2);
    __bf16* rppb = (__bf16*)alloc((size_t)20032 * 128 / 2);
    __bf16* rgpb = (__bf16*)alloc((size_t)20032 * 128 / 2);
    // R1: xpb+xgb during proj; wpp,wgp,haggb after
    char* R1 = (char*)alloc((size_t)5128192 + 2588672);
    __bf16* xpb = (__bf16*)R1;                             // 20032*512
    __bf16* xgb = (__bf16*)(R1 + (size_t)20032 * 512 * 2); // 5056*1024
    float*  wpp = (float*)R1;                              // 20000*128
    float*  wgp = wpp + (size_t)20000 * 128;
    __bf16* haggb = (__bf16*)(wgp + (size_t)20000 * 128);  // 25024*128
    __bf16* w1pt = (__bf16*)alloc(128 * 512 / 2);
    __bf16* w1gt = (__bf16*)alloc(128 * 1024 / 2);
    __bf16* wlpt = (__bf16*)alloc(128 * 128 / 2);
    __bf16* wrpt = (__bf16*)alloc(128 * 128 / 2);
    __bf16* wrgt = (__bf16*)alloc(128 * 128 / 2);
    __bf16* wnlt = (__bf16*)alloc(128 * 128 / 2);
    __bf16* wnrt = (__bf16*)alloc(128 * 128 / 2);
    __bf16* wfct = (__bf16*)alloc(1024 * 128 / 2);
    int* ibase = (int*)alloc(140000 + 25001 + 440000);
    int* outdeg_pp = ibase;
    int* outdeg_pg = outdeg_pp + NP;
    int* outdeg_gp = outdeg_pg + NP;
    int* indeg_pp  = outdeg_gp + NG;
    int* indeg_gp  = indeg_pp + NP;
    int* indeg_pg  = indeg_gp + NP;
    int* cnt       = indeg_pg + NG;
    int* fill      = cnt + NTOT;
    int* row_ptr   = fill + NTOT;
    int* payload   = row_ptr + NTOT + 1;
    float* escale  = (float*)alloc(440000);

    hipMemsetAsync(ibase, 0, (size_t)140000 * sizeof(int), stream);

    const int EB = (ETOT + 255) / 256;
    hist_kernel<<<EB, 256, 0, stream>>>(src_pp, dst_pp, src_pg, dst_pg, src_gp, dst_gp,
                                        outdeg_pp, outdeg_pg, outdeg_gp,
                                        indeg_pp, indeg_gp, indeg_pg, cnt);
    scan_kernel<<<1, 1024, 0, stream>>>(cnt, row_ptr);
    scatter_kernel<<<EB, 256, 0, stream>>>(src_pp, dst_pp, src_pg, dst_pg, src_gp, dst_gp,
                                           outdeg_pp, outdeg_pg, outdeg_gp,
                                           row_ptr, fill, payload, escale);

    conv_x_kernel<<<dim3(5008, 2), 256, 0, stream>>>(x_protein, x_go, xpb, xgb);
    conv_w_kernel<<<dim3(512, 8), 256, 0, stream>>>(W1p, W1g, Wl_p, Wr_p, Wr_g, Wnl, Wnr, Wfc,
                                                    w1pt, w1gt, wlpt, wrpt, wrgt, wnlt, wnrt, wfct);

    // fused projections + l2norm -> xb (bf16): blocks [0,313) protein, [313,392) go
    {
        GJob p0 = { xpb, nullptr, w1pt, nullptr, b1p, nullptr, nullptr, nullptr, xb, NP, 128, 512, 16 };
        GJob p1 = { xgb, nullptr, w1gt, nullptr, b1g, nullptr, nullptr, nullptr,
                    xb + (size_t)NP * 128, NG, 128, 1024, 32 };
        gemm_bt<2, 0, 0, 2><<<392, 256, 0, stream>>>(p0, p1, 313);
    }

    // GCN aggregation for type attention (protein dst only)
    rst_agg_kernel<<<NP, 128, 0, stream>>>(xb, row_ptr, payload, escale, indeg_pp, indeg_gp, rppb, rgpb);

    // fused ea: wpp = elu(x@Wl_p + rpp@Wr_p + ...); wgp = elu(x@Wl_p + rgp@Wr_g + ...)
    {
        GJob e0 = { xb, rppb, wlpt, wrpt, bl_p, br_p, wpp, nullptr, nullptr, NP, 128, 128, 4 };
        GJob e1 = { xb, rgpb, wlpt, wrgt, bl_p, br_g, wgp, nullptr, nullptr, NP, 128, 128, 4 };
        gemm_bt<1, 1, 0, 0><<<626, 256, 0, stream>>>(e0, e1, 313);
    }

    // type-level alpha weights (in-place over wpp/wgp)
    wa_kernel<<<(NP * DH + 255) / 256, 256, 0, stream>>>(indeg_pp, indeg_gp, wpp, wgp);

    // node attention projections: Ob(bf16) = x@Wnl+bnl = hl; O2(fp32) = x@Wnr+bnr = hr
    {
        GJob h0 = { xb, nullptr, wnlt, wnrt, bnl, bnr, nullptr, hr, hlb, NTOT, 128, 128, 4 };
        gemm_bt<0, 0, 1, 2><<<391, 256, 0, stream>>>(h0, h0, 1 << 30);
    }

    // node attention + aggregation -> haggb (bf16)
    node_attn_kernel<<<NTOT, 128, 0, stream>>>(xb, hlb, hr, wpp, wgp, indeg_pg, row_ptr, payload, haggb);

    // final classifier: out = hagg@Wfc + bfc
    {
        GJob o0 = { haggb, nullptr, wfct, nullptr, bfc, nullptr, out, nullptr, nullptr, NTOT, NCLS, 128, 4 };
        gemm_bt<0, 0, 0, 0><<<dim3(391, 8), 256, 0, stream>>>(o0, o0, 1 << 30);
    }

    (void)in_sizes; (void)n_in; (void)out_size; (void)ws_size;
}